// Round 12
// baseline (1766.874 us; speedup 1.0000x reference)
//
#include <hip/hip_runtime.h>
#include <cstdint>

#define BB 256
#define TT 4096
#define FDIM 16
#define HH 128
#define CH 32           // timesteps per chunk
#define NCH (TT / CH)   // 128 chunks
#define NPROD 14        // producer waves 0-13; wave 14 = scan1, wave 15 = scan2+3
#define NTHR 1024

typedef unsigned long long u64;
typedef float f32x2 __attribute__((ext_vector_type(2)));
typedef uint32_t u32x4 __attribute__((ext_vector_type(4)));

// ---------------------------------------------------------------------------
// asm helpers. Loads are asm volatile with explicit waits. SAFETY RULE
// (round-9 failure): keep task live-sets well under the 128-VGPR cap so the
// compiler never copies/spills an asm-output register before its wait.
// ---------------------------------------------------------------------------
__device__ __forceinline__ uint32_t lds_addr32(const void* p) {
  return (uint32_t)(uintptr_t)p;
}
__device__ __forceinline__ f32x2 glb_load_b64(uint32_t voff, const void* base) {
  f32x2 d;
  asm volatile("global_load_dwordx2 %0, %1, %2" : "=v"(d) : "v"(voff), "s"(base));
  return d;
}
__device__ __forceinline__ void ds_write_b128_at(uint32_t addr, u32x4 v) {
  asm volatile("ds_write_b128 %0, %1" ::"v"(addr), "v"(v));
}
#define DSW32(A, D) asm volatile("ds_write_b32 %0, %1" ::"v"(A), "v"(D));
#define WAIT_VM(N)                                          \
  {                                                         \
    asm volatile("s_waitcnt vmcnt(" #N ")" ::: "memory");   \
    __builtin_amdgcn_sched_barrier(0);                      \
  }
#define WAIT_LGKM(N)                                        \
  {                                                         \
    asm volatile("s_waitcnt lgkmcnt(" #N ")" ::: "memory"); \
    __builtin_amdgcn_sched_barrier(0);                      \
  }
#define DSR64(D, A, OFF) \
  asm volatile("ds_read_b64 %0, %1 offset:" #OFF : "=v"(D) : "v"(A));
#define DSR128(D, A, OFF) \
  asm volatile("ds_read_b128 %0, %1 offset:" #OFF : "=v"(D) : "v"(A));
#define DS_READ_OFF(D, A, OFF) \
  asm volatile("ds_read_b32 %0, %1 offset:" #OFF : "=v"(D) : "v"(A));
#define DSRU32(D, A, OFF) \
  asm volatile("ds_read_b32 %0, %1 offset:" #OFF : "=v"(D) : "v"(A));

// Packed fp32 add (two independent IEEE-rn adds; dataflow pins association).
__device__ __forceinline__ f32x2 pk_add(f32x2 a, f32x2 b) {
  f32x2 d;
  asm("v_pk_add_f32 %0, %1, %2" : "=v"(d) : "v"(a), "v"(b));
  return d;
}
__device__ __forceinline__ u64 rfl64(u64 x) {
  uint32_t lo = (uint32_t)__builtin_amdgcn_readfirstlane((int)(uint32_t)x);
  uint32_t hi = (uint32_t)__builtin_amdgcn_readfirstlane((int)(uint32_t)(x >> 32));
  return ((u64)hi << 32) | lo;
}
// 64-lane DPP sum; result valid in lane 63 (same op sequence as rounds 1-11).
__device__ __forceinline__ float wave_red_add63(float v) {
#define DPP_ADD(c)                                                             \
  v += __int_as_float(                                                         \
      __builtin_amdgcn_update_dpp(0, __float_as_int(v), c, 0xF, 0xF, true))
  DPP_ADD(0x111);
  DPP_ADD(0x112);
  DPP_ADD(0x114);
  DPP_ADD(0x118);
  DPP_ADD(0x142);
  DPP_ADD(0x143);
#undef DPP_ADD
  return v;
}

// ---------------------------------------------------------------------------
// Kernel 0: transposed weights in workspace.
// w1t: 64 rows of 512B; rows 0..31 real, 32..63 zero (guard-bit sentinels).
// w2t: 129 rows; rows 0..127 real, row 128 zero (sentinel).
// ---------------------------------------------------------------------------
__global__ __launch_bounds__(64) void snn_prep(const float* __restrict__ W1,
                                               const float* __restrict__ W2,
                                               f32x2* __restrict__ w1t,
                                               f32x2* __restrict__ w2t) {
  const int l = threadIdx.x;
  for (int j = 0; j < 64; ++j)
    w1t[j * 64 + l] = (j < 32) ? f32x2{W1[l * 32 + j], W1[(64 + l) * 32 + j]}
                               : f32x2{0.f, 0.f};
  for (int j = 0; j < 129; ++j)
    w2t[j * 64 + l] = (j < 128) ? f32x2{W2[l * 128 + j], W2[(64 + l) * 128 + j]}
                                : f32x2{0.f, 0.f};
}

// ---------------------------------------------------------------------------
// Kernel 1: delta encode -> 32-bit masks (verbatim from passing rounds 4-11).
// ---------------------------------------------------------------------------
__global__ __launch_bounds__(64) void snn_encode(const float* __restrict__ x,
                                                 uint32_t* __restrict__ masks) {
  __shared__ float tile[2][4][64][16];  // 32 KiB
  const int lane = threadIdx.x;
  const int sub = lane >> 4;
  const int f = lane & 15;
  const int b0 = blockIdx.x * 4;
  float ref = x[(size_t)(b0 + sub) * (TT * FDIM) + f];

  const float4* xv = (const float4*)x;
  float4 ld[16];
#define K1_ISSUE(G)                                                           \
  _Pragma("unroll") for (int k = 0; k < 16; ++k) {                            \
    int idx4 = k * 64 + lane;                                                 \
    int bl = idx4 >> 8;                                                       \
    int r = idx4 & 255;                                                       \
    ld[k] = xv[(size_t)(b0 + bl) * (TT * 4) + (size_t)(G) * 256 + r];         \
  }
#define K1_WRITE(BUF)                                                         \
  _Pragma("unroll") for (int k = 0; k < 16; ++k) {                            \
    int idx4 = k * 64 + lane;                                                 \
    int bl = idx4 >> 8;                                                       \
    int r = idx4 & 255;                                                       \
    ((float4*)&tile[BUF][bl][0][0])[r] = ld[k];                               \
  }
#define CHUNK_ISSUE(ARR, A)                                                   \
  {                                                                           \
    DS_READ_OFF(ARR[0], A, 0);                                                \
    DS_READ_OFF(ARR[1], A, 64);                                               \
    DS_READ_OFF(ARR[2], A, 128);                                              \
    DS_READ_OFF(ARR[3], A, 192);                                              \
    DS_READ_OFF(ARR[4], A, 256);                                              \
    DS_READ_OFF(ARR[5], A, 320);                                              \
    DS_READ_OFF(ARR[6], A, 384);                                              \
    DS_READ_OFF(ARR[7], A, 448);                                              \
  }
#define PROC8(ARR, TBASE)                                                     \
  _Pragma("unroll") for (int i = 0; i < 8; ++i) {                             \
    float cur = ARR[i];                                                       \
    float diff = cur - ref;                                                   \
    bool onb = diff >= 0.5f;                                                  \
    bool offb = diff <= -0.5f;                                                \
    u64 bon = __ballot(onb);                                                  \
    u64 boff = __ballot(offb);                                                \
    ref = (onb || offb) ? cur : ref;                                          \
    if (f == 0) {                                                             \
      uint32_t mk = (uint32_t)((bon >> (sub * 16)) & 0xFFFFull) |             \
                    ((uint32_t)((boff >> (sub * 16)) & 0xFFFFull) << 16);     \
      masks[(size_t)(b0 + sub) * TT + ((TBASE) + i)] = mk;                    \
    }                                                                         \
  }

  const uint32_t tbase =
      lds_addr32(&tile[0][0][0][0]) + (uint32_t)sub * 4096u + (uint32_t)f * 4u;

  K1_ISSUE(0);
  K1_WRITE(0);
  WAIT_LGKM(0);
  for (int g = 0; g < TT / 64; ++g) {
    if (g + 1 < TT / 64) K1_ISSUE(g + 1);
    const int buf = g & 1;
    const uint32_t caddr = tbase + (uint32_t)buf * 16384u;
    float va[8], vb[8];
    CHUNK_ISSUE(va, caddr);
#pragma unroll
    for (int c = 0; c < 8; ++c) {
      if (c < 7) {
        uint32_t an = caddr + (uint32_t)(c + 1) * 512u;
        if (c & 1) {
          CHUNK_ISSUE(va, an);
        } else {
          CHUNK_ISSUE(vb, an);
        }
        WAIT_LGKM(8);
      } else {
        WAIT_LGKM(0);
      }
      if (c & 1) {
        PROC8(vb, g * 64 + c * 8);
      } else {
        PROC8(va, g * 64 + c * 8);
      }
    }
    if (g + 1 < TT / 64) {
      K1_WRITE((g + 1) & 1);
      WAIT_LGKM(0);
    }
  }
#undef PROC8
#undef CHUNK_ISSUE
#undef K1_WRITE
#undef K1_ISSUE
}

// ---------------------------------------------------------------------------
// Kernel 2: specialized-wave SNN core, 16 waves/block, one block per batch.
// Round-12 rebalance vs passing round 10:
//  - scan1 slimmed to LIF1 + ballots + raw S1 write (~10 instr/step);
//    producers extract C2 indices themselves (R7's proven merged EXTRACT).
//  - IDX0/IDX1/S1R/CNT machinery deleted; producers extract C1 indices from
//    mks directly via the guard-bit trick (rows 32+ of w1t are zeros).
//  - wave 15 runs only scan2 + scan3.
// Parity/dependency scheme unchanged (S1 follows the proven S2 pattern).
// ---------------------------------------------------------------------------
__global__ __launch_bounds__(NTHR, 1) void snn_core12(
    const uint32_t* __restrict__ masks, const f32x2* __restrict__ w1t,
    const f32x2* __restrict__ w2t, const float* __restrict__ b1,
    const float* __restrict__ b2, const float* __restrict__ W3,
    const float* __restrict__ b3, float* __restrict__ out) {
  __shared__ __align__(16) uint32_t mks[TT];   // 16 KB input masks
  __shared__ f32x2 C1b[2][CH][64];             // 32 KB
  __shared__ f32x2 C2b[2][CH][64];             // 32 KB
  __shared__ f32x2 C3b[2][CH];                 // 512 B
  __shared__ __align__(16) u64 S1[2][CH][2];   // 1 KB spk1 ballots
  __shared__ __align__(16) u64 S2[2][CH][2];   // 1 KB spk2 ballots

  const int tid = threadIdx.x;
  const int lane = tid & 63;
  const int wv = tid >> 6;
  const int b = blockIdx.x;
  const uint32_t lane8 = (uint32_t)lane * 8u;

  {  // stage this batch's masks into LDS (coalesced)
    const u32x4* src = (const u32x4*)(masks + (size_t)b * TT);
    u32x4* dst = (u32x4*)mks;
    for (int i = tid; i < TT / 4; i += NTHR) dst[i] = src[i];
  }
  const f32x2 bias1 = {b1[lane], b1[64 + lane]};
  const f32x2 bias2 = {b2[lane], b2[64 + lane]};
  const float w30a = W3[lane], w30b = W3[64 + lane];
  const float w31a = W3[128 + lane], w31b = W3[192 + lane];
  const float b30 = b3[0], b31 = b3[1];
  float m1a = 0.f, m1b = 0.f, m2a = 0.f, m2b = 0.f, m3x = 0.f, m3y = 0.f;
  float2* outv = (float2*)out;

  const uint32_t mksb = lds_addr32(&mks[0]);
  const uint32_t s1b = lds_addr32(&S1[0][0][0]);
  const uint32_t s2b = lds_addr32(&S2[0][0][0]);

// merged ascending extraction over (a_: j 0-63, b_: j 64-127); sentinel 128
// when exhausted (row 128 of w2t is zeros). Proven in rounds 4-7.
#define EXTRACT(J)                                                            \
  {                                                                           \
    bool av_ = (a_ != 0);                                                     \
    bool bv_ = (b_ != 0);                                                     \
    uint32_t ja_ = av_ ? (uint32_t)__builtin_ctzll(a_) : 0u;                  \
    uint32_t jb_ = bv_ ? 64u + (uint32_t)__builtin_ctzll(b_) : 128u;          \
    J = av_ ? ja_ : jb_;                                                      \
    u64 an_ = a_ & (a_ - 1);                                                  \
    u64 bn_ = b_ & (b_ - 1);                                                  \
    b_ = (!av_ && bv_) ? bn_ : b_;                                            \
    a_ = av_ ? an_ : a_;                                                      \
  }

// ---- producer tasks: self-contained, WAIT before consume (R10 shape) ----
#define C1_TASK(TASK)                                                         \
  {                                                                           \
    uint32_t mk_;                                                             \
    DSRU32(mk_, mksb + (uint32_t)((k * CH + (TASK)) * 4), 0);                 \
    WAIT_LGKM(0);                                                             \
    mk_ = (uint32_t)__builtin_amdgcn_readfirstlane((int)mk_);                 \
    u64 mm_ = (u64)mk_ | 0xFFFF00000000ull; /* guard bits 32..47 -> zeros */  \
    f32x2 B[16];                                                              \
    _Pragma("unroll") for (int s = 0; s < 16; ++s) {                          \
      uint32_t j_ = (uint32_t)__builtin_ctzll(mm_);                           \
      mm_ &= mm_ - 1;                                                         \
      B[s] = glb_load_b64((j_ << 9) + lane8, w1t);                            \
    }                                                                         \
    WAIT_VM(0);                                                               \
    f32x2 c_ = {0.f, 0.f};                                                    \
    _Pragma("unroll") for (int s = 0; s < 16; ++s) c_ = pk_add(c_, B[s]);     \
    c_ = pk_add(c_, bias1);                                                   \
    C1b[k & 1][(TASK)][lane] = c_;                                            \
  }
#define C2_TASK(TASK, C2Q)                                                    \
  {                                                                           \
    u32x4 qs_;                                                                \
    DSR128(qs_, s1b + (uint32_t)((((C2Q)&1) * CH + (TASK)) * 16), 0);         \
    WAIT_LGKM(0);                                                             \
    u64 a_ = rfl64((u64)qs_.x | ((u64)qs_.y << 32));                          \
    u64 b_ = rfl64((u64)qs_.z | ((u64)qs_.w << 32));                          \
    f32x2 B[24];                                                              \
    _Pragma("unroll") for (int s = 0; s < 24; ++s) {                          \
      uint32_t j_;                                                            \
      EXTRACT(j_);                                                            \
      B[s] = glb_load_b64((j_ << 9) + lane8, w2t);                            \
    }                                                                         \
    WAIT_VM(0);                                                               \
    f32x2 c_ = {0.f, 0.f};                                                    \
    _Pragma("unroll") for (int s = 0; s < 24; ++s) c_ = pk_add(c_, B[s]);     \
    while (a_) { /* rare >24-spike tails: exact ascending order */            \
      uint32_t j_ = (uint32_t)__builtin_ctzll(a_);                            \
      a_ &= a_ - 1;                                                           \
      f32x2 tw_ = glb_load_b64((j_ << 9) + lane8, w2t);                       \
      WAIT_VM(0);                                                             \
      c_ = pk_add(c_, tw_);                                                   \
    }                                                                         \
    while (b_) {                                                              \
      uint32_t j_ = 64u + (uint32_t)__builtin_ctzll(b_);                      \
      b_ &= b_ - 1;                                                           \
      f32x2 tw_ = glb_load_b64((j_ << 9) + lane8, w2t);                       \
      WAIT_VM(0);                                                             \
      c_ = pk_add(c_, tw_);                                                   \
    }                                                                         \
    c_ = pk_add(c_, bias2);                                                   \
    C2b[(C2Q)&1][(TASK)][lane] = c_;                                          \
  }
#define C3_TASK(T3)                                                           \
  {                                                                           \
    int c3_ = k - 4;                                                          \
    if (c3_ >= 0 && c3_ < NCH) {                                              \
      u64 a_ = rfl64(S2[c3_ & 1][(T3)][0]);                                   \
      u64 b_ = rfl64(S2[c3_ & 1][(T3)][1]);                                   \
      float v0 = (((a_ >> lane) & 1) ? w30a : 0.f) +                          \
                 (((b_ >> lane) & 1) ? w30b : 0.f);                           \
      float v1 = (((a_ >> lane) & 1) ? w31a : 0.f) +                          \
                 (((b_ >> lane) & 1) ? w31b : 0.f);                           \
      float r0 = wave_red_add63(v0);                                          \
      float r1 = wave_red_add63(v1);                                          \
      if (lane == 63) C3b[c3_ & 1][(T3)] = f32x2{r0 + b30, r1 + b31};         \
    }                                                                         \
  }

// ---- scan helpers: 16-wide issue groups (low register pressure) ----
#define ISSUE16_512(ARR, A)                                                   \
  {                                                                           \
    DSR64(ARR[0], A, 0);     DSR64(ARR[1], A, 512);                           \
    DSR64(ARR[2], A, 1024);  DSR64(ARR[3], A, 1536);                          \
    DSR64(ARR[4], A, 2048);  DSR64(ARR[5], A, 2560);                          \
    DSR64(ARR[6], A, 3072);  DSR64(ARR[7], A, 3584);                          \
    DSR64(ARR[8], A, 4096);  DSR64(ARR[9], A, 4608);                          \
    DSR64(ARR[10], A, 5120); DSR64(ARR[11], A, 5632);                         \
    DSR64(ARR[12], A, 6144); DSR64(ARR[13], A, 6656);                         \
    DSR64(ARR[14], A, 7168); DSR64(ARR[15], A, 7680);                         \
  }
#define ISSUE16_8(ARR, A)                                                     \
  {                                                                           \
    DSR64(ARR[0], A, 0);   DSR64(ARR[1], A, 8);                               \
    DSR64(ARR[2], A, 16);  DSR64(ARR[3], A, 24);                              \
    DSR64(ARR[4], A, 32);  DSR64(ARR[5], A, 40);                              \
    DSR64(ARR[6], A, 48);  DSR64(ARR[7], A, 56);                              \
    DSR64(ARR[8], A, 64);  DSR64(ARR[9], A, 72);                              \
    DSR64(ARR[10], A, 80); DSR64(ARR[11], A, 88);                             \
    DSR64(ARR[12], A, 96); DSR64(ARR[13], A, 104);                            \
    DSR64(ARR[14], A, 112); DSR64(ARR[15], A, 120);                           \
  }
// scan half: 16 LIF steps + raw ballot writes (lane 0). Same shape for
// scan1 (-> S1) and scan2 (-> S2).
#define SCANL_HALF(SB, TB, MA, MB)                                            \
  _Pragma("unroll") for (int i = 0; i < 16; ++i) {                            \
    f32x2 cv_ = arr_[i];                                                      \
    float n0_ = __fadd_rn(__fmul_rn(0.9f, MA), cv_.x);                        \
    float n1_ = __fadd_rn(__fmul_rn(0.9f, MB), cv_.y);                        \
    MA = (MA > 1.f) ? (n0_ - 1.f) : n0_;                                      \
    MB = (MB > 1.f) ? (n1_ - 1.f) : n1_;                                      \
    u64 s0_ = __ballot(MA > 1.f);                                             \
    u64 s1_ = __ballot(MB > 1.f);                                             \
    if (lane == 0)                                                            \
      ds_write_b128_at((SB) + (uint32_t)(((TB) + i) * 16),                    \
                       u32x4{(uint32_t)s0_, (uint32_t)(s0_ >> 32),            \
                             (uint32_t)s1_, (uint32_t)(s1_ >> 32)});          \
  }
#define SCANL(CHK, CBUF, SBASE, MA, MB)                                       \
  {                                                                           \
    const int par_ = (CHK) & 1;                                               \
    const uint32_t rb_ = lds_addr32(&CBUF[par_][0][0]) + lane8;               \
    const uint32_t sb_ = (SBASE) + (uint32_t)(par_ * CH * 16);                \
    f32x2 arr_[16];                                                           \
    ISSUE16_512(arr_, rb_);                                                   \
    WAIT_LGKM(0);                                                             \
    SCANL_HALF(sb_, 0, MA, MB)                                                \
    const uint32_t rb2_ = rb_ + 8192u;                                        \
    ISSUE16_512(arr_, rb2_);                                                  \
    WAIT_LGKM(0);                                                             \
    SCANL_HALF(sb_, 16, MA, MB)                                               \
    WAIT_LGKM(0);                                                             \
  }
#define SCAN3_HALF(CHK, TB)                                                   \
  _Pragma("unroll") for (int i = 0; i < 16; ++i) {                            \
    f32x2 c3_ = arr_[i];                                                      \
    float e0_ = __fadd_rn(__fmul_rn(0.9f, m3x), c3_.x);                       \
    float e1_ = __fadd_rn(__fmul_rn(0.9f, m3y), c3_.y);                       \
    m3x = (m3x > 1.f) ? (e0_ - 1.f) : e0_;                                    \
    m3y = (m3y > 1.f) ? (e1_ - 1.f) : e1_;                                    \
    if (lane == 0)                                                            \
      outv[(size_t)((CHK)*CH + (TB) + i) * BB + b] = make_float2(m3x, m3y);   \
  }
#define SCAN3(CHK)                                                            \
  {                                                                           \
    const int par_ = (CHK) & 1;                                               \
    const uint32_t cb_ = lds_addr32(&C3b[par_][0]);                           \
    f32x2 arr_[16];                                                           \
    ISSUE16_8(arr_, cb_);                                                     \
    WAIT_LGKM(0);                                                             \
    SCAN3_HALF(CHK, 0)                                                        \
    const uint32_t cb2_ = cb_ + 128u;                                         \
    ISSUE16_8(arr_, cb2_);                                                    \
    WAIT_LGKM(0);                                                             \
    SCAN3_HALF(CHK, 16)                                                       \
  }

  // ================= chunk-synchronous main pipeline =================
  for (int k = 0; k < NCH + 5; ++k) {
    __syncthreads();
    if (wv < NPROD) {
      // tasks 0..31 = C1(chunk k), 32..63 = C2(chunk k-2); skip out-of-range.
      for (int ti = wv; ti < 2 * CH; ti += NPROD) {
        if (ti < CH) {
          if (k < NCH) C1_TASK(ti);
        } else {
          int c2q = k - 2;
          if (c2q >= 0 && c2q < NCH) C2_TASK(ti - CH, c2q);
        }
      }
      for (int t3 = wv; t3 < CH; t3 += NPROD) {
        C3_TASK(t3);
      }
    } else if (wv == 14) {
      if (k >= 1 && k - 1 < NCH) SCANL(k - 1, C1b, s1b, m1a, m1b);
    } else {
      if (k >= 3 && k - 3 < NCH) SCANL(k - 3, C2b, s2b, m2a, m2b);
      if (k >= 5 && k - 5 < NCH) SCAN3(k - 5);
    }
  }
#undef SCAN3
#undef SCAN3_HALF
#undef SCANL
#undef SCANL_HALF
#undef ISSUE16_8
#undef ISSUE16_512
#undef C3_TASK
#undef C2_TASK
#undef C1_TASK
#undef EXTRACT
}

extern "C" void kernel_launch(void* const* d_in, const int* in_sizes, int n_in,
                              void* d_out, int out_size, void* d_ws,
                              size_t ws_size, hipStream_t stream) {
  const float* x = (const float*)d_in[0];
  const float* W1 = (const float*)d_in[1];
  const float* b1 = (const float*)d_in[2];
  const float* W2 = (const float*)d_in[3];
  const float* b2 = (const float*)d_in[4];
  const float* W3 = (const float*)d_in[5];
  const float* b3 = (const float*)d_in[6];
  float* out = (float*)d_out;

  uint32_t* masks = (uint32_t*)d_ws;                         // 4 MiB
  char* wbase = (char*)d_ws + (size_t)BB * TT * 4;
  f32x2* w1t = (f32x2*)wbase;                                // 32768 B
  f32x2* w2t = (f32x2*)(wbase + 32768);                      // 66048 B

  snn_prep<<<1, 64, 0, stream>>>(W1, W2, w1t, w2t);
  snn_encode<<<BB / 4, 64, 0, stream>>>(x, masks);
  snn_core12<<<BB, NTHR, 0, stream>>>(masks, w1t, w2t, b1, b2, W3, b3, out);
}

// Round 13
// 1582.809 us; speedup vs baseline: 1.1163x; 1.1163x over previous
//
#include <hip/hip_runtime.h>
#include <cstdint>

#define BB 256
#define TT 4096
#define FDIM 16
#define HH 128
#define CH 64           // timesteps per chunk (doubled: halves iteration count)
#define NCH (TT / CH)   // 64 chunks
#define NPROD 13        // waves 0-12 producers; 13=scan1, 14=scan2+3, 15=IDX0
#define NTHR 1024

typedef unsigned long long u64;
typedef float f32x2 __attribute__((ext_vector_type(2)));
typedef uint32_t u32x4 __attribute__((ext_vector_type(4)));

// ---------------------------------------------------------------------------
// asm helpers. Loads are asm volatile with explicit waits. SAFETY RULE
// (round-9 failure): keep task live-sets well under the 128-VGPR cap so the
// compiler never copies/spills an asm-output register before its wait.
// ---------------------------------------------------------------------------
__device__ __forceinline__ uint32_t lds_addr32(const void* p) {
  return (uint32_t)(uintptr_t)p;
}
__device__ __forceinline__ f32x2 glb_load_b64(uint32_t voff, const void* base) {
  f32x2 d;
  asm volatile("global_load_dwordx2 %0, %1, %2" : "=v"(d) : "v"(voff), "s"(base));
  return d;
}
__device__ __forceinline__ void ds_write_b128_at(uint32_t addr, u32x4 v) {
  asm volatile("ds_write_b128 %0, %1" ::"v"(addr), "v"(v));
}
#define DSW32(A, D) asm volatile("ds_write_b32 %0, %1" ::"v"(A), "v"(D));
#define DSW64(A, D) asm volatile("ds_write_b64 %0, %1" ::"v"(A), "v"(D));
#define WAIT_VM(N)                                          \
  {                                                         \
    asm volatile("s_waitcnt vmcnt(" #N ")" ::: "memory");   \
    __builtin_amdgcn_sched_barrier(0);                      \
  }
#define WAIT_LGKM(N)                                        \
  {                                                         \
    asm volatile("s_waitcnt lgkmcnt(" #N ")" ::: "memory"); \
    __builtin_amdgcn_sched_barrier(0);                      \
  }
#define DSR64(D, A, OFF) \
  asm volatile("ds_read_b64 %0, %1 offset:" #OFF : "=v"(D) : "v"(A));
#define DSR128(D, A, OFF) \
  asm volatile("ds_read_b128 %0, %1 offset:" #OFF : "=v"(D) : "v"(A));
#define DS_READ_OFF(D, A, OFF) \
  asm volatile("ds_read_b32 %0, %1 offset:" #OFF : "=v"(D) : "v"(A));

// Packed fp32 add (two independent IEEE-rn adds; dataflow pins association).
__device__ __forceinline__ f32x2 pk_add(f32x2 a, f32x2 b) {
  f32x2 d;
  asm("v_pk_add_f32 %0, %1, %2" : "=v"(d) : "v"(a), "v"(b));
  return d;
}
__device__ __forceinline__ u64 rfl64(u64 x) {
  uint32_t lo = (uint32_t)__builtin_amdgcn_readfirstlane((int)(uint32_t)x);
  uint32_t hi = (uint32_t)__builtin_amdgcn_readfirstlane((int)(uint32_t)(x >> 32));
  return ((u64)hi << 32) | lo;
}
__device__ __forceinline__ uint32_t mbcnt64(u64 m) {
  uint32_t r = __builtin_amdgcn_mbcnt_lo((uint32_t)m, 0u);
  return __builtin_amdgcn_mbcnt_hi((uint32_t)(m >> 32), r);
}
// 64-lane DPP sum; result valid in lane 63 (same op sequence as rounds 1-12).
__device__ __forceinline__ float wave_red_add63(float v) {
#define DPP_ADD(c)                                                             \
  v += __int_as_float(                                                         \
      __builtin_amdgcn_update_dpp(0, __float_as_int(v), c, 0xF, 0xF, true))
  DPP_ADD(0x111);
  DPP_ADD(0x112);
  DPP_ADD(0x114);
  DPP_ADD(0x118);
  DPP_ADD(0x142);
  DPP_ADD(0x143);
#undef DPP_ADD
  return v;
}

// ---------------------------------------------------------------------------
// Kernel 0: transposed weights in workspace.
// w1t: 64 rows of 512B; rows 0..31 real, 32..63 zero (sentinels).
// w2t: 129 rows; rows 0..127 real, row 128 zero (sentinel).
// ---------------------------------------------------------------------------
__global__ __launch_bounds__(64) void snn_prep(const float* __restrict__ W1,
                                               const float* __restrict__ W2,
                                               f32x2* __restrict__ w1t,
                                               f32x2* __restrict__ w2t) {
  const int l = threadIdx.x;
  for (int j = 0; j < 64; ++j)
    w1t[j * 64 + l] = (j < 32) ? f32x2{W1[l * 32 + j], W1[(64 + l) * 32 + j]}
                               : f32x2{0.f, 0.f};
  for (int j = 0; j < 129; ++j)
    w2t[j * 64 + l] = (j < 128) ? f32x2{W2[l * 128 + j], W2[(64 + l) * 128 + j]}
                                : f32x2{0.f, 0.f};
}

// ---------------------------------------------------------------------------
// Kernel 1: delta encode -> 32-bit masks (verbatim from passing rounds 4-12).
// ---------------------------------------------------------------------------
__global__ __launch_bounds__(64) void snn_encode(const float* __restrict__ x,
                                                 uint32_t* __restrict__ masks) {
  __shared__ float tile[2][4][64][16];  // 32 KiB
  const int lane = threadIdx.x;
  const int sub = lane >> 4;
  const int f = lane & 15;
  const int b0 = blockIdx.x * 4;
  float ref = x[(size_t)(b0 + sub) * (TT * FDIM) + f];

  const float4* xv = (const float4*)x;
  float4 ld[16];
#define K1_ISSUE(G)                                                           \
  _Pragma("unroll") for (int k = 0; k < 16; ++k) {                            \
    int idx4 = k * 64 + lane;                                                 \
    int bl = idx4 >> 8;                                                       \
    int r = idx4 & 255;                                                       \
    ld[k] = xv[(size_t)(b0 + bl) * (TT * 4) + (size_t)(G) * 256 + r];         \
  }
#define K1_WRITE(BUF)                                                         \
  _Pragma("unroll") for (int k = 0; k < 16; ++k) {                            \
    int idx4 = k * 64 + lane;                                                 \
    int bl = idx4 >> 8;                                                       \
    int r = idx4 & 255;                                                       \
    ((float4*)&tile[BUF][bl][0][0])[r] = ld[k];                               \
  }
#define CHUNK_ISSUE(ARR, A)                                                   \
  {                                                                           \
    DS_READ_OFF(ARR[0], A, 0);                                                \
    DS_READ_OFF(ARR[1], A, 64);                                               \
    DS_READ_OFF(ARR[2], A, 128);                                              \
    DS_READ_OFF(ARR[3], A, 192);                                              \
    DS_READ_OFF(ARR[4], A, 256);                                              \
    DS_READ_OFF(ARR[5], A, 320);                                              \
    DS_READ_OFF(ARR[6], A, 384);                                              \
    DS_READ_OFF(ARR[7], A, 448);                                              \
  }
#define PROC8(ARR, TBASE)                                                     \
  _Pragma("unroll") for (int i = 0; i < 8; ++i) {                             \
    float cur = ARR[i];                                                       \
    float diff = cur - ref;                                                   \
    bool onb = diff >= 0.5f;                                                  \
    bool offb = diff <= -0.5f;                                                \
    u64 bon = __ballot(onb);                                                  \
    u64 boff = __ballot(offb);                                                \
    ref = (onb || offb) ? cur : ref;                                          \
    if (f == 0) {                                                             \
      uint32_t mk = (uint32_t)((bon >> (sub * 16)) & 0xFFFFull) |             \
                    ((uint32_t)((boff >> (sub * 16)) & 0xFFFFull) << 16);     \
      masks[(size_t)(b0 + sub) * TT + ((TBASE) + i)] = mk;                    \
    }                                                                         \
  }

  const uint32_t tbase =
      lds_addr32(&tile[0][0][0][0]) + (uint32_t)sub * 4096u + (uint32_t)f * 4u;

  K1_ISSUE(0);
  K1_WRITE(0);
  WAIT_LGKM(0);
  for (int g = 0; g < TT / 64; ++g) {
    if (g + 1 < TT / 64) K1_ISSUE(g + 1);
    const int buf = g & 1;
    const uint32_t caddr = tbase + (uint32_t)buf * 16384u;
    float va[8], vb[8];
    CHUNK_ISSUE(va, caddr);
#pragma unroll
    for (int c = 0; c < 8; ++c) {
      if (c < 7) {
        uint32_t an = caddr + (uint32_t)(c + 1) * 512u;
        if (c & 1) {
          CHUNK_ISSUE(va, an);
        } else {
          CHUNK_ISSUE(vb, an);
        }
        WAIT_LGKM(8);
      } else {
        WAIT_LGKM(0);
      }
      if (c & 1) {
        PROC8(vb, g * 64 + c * 8);
      } else {
        PROC8(va, g * 64 + c * 8);
      }
    }
    if (g + 1 < TT / 64) {
      K1_WRITE((g + 1) & 1);
      WAIT_LGKM(0);
    }
  }
#undef PROC8
#undef CHUNK_ISSUE
#undef K1_WRITE
#undef K1_ISSUE
}

// ---------------------------------------------------------------------------
// Kernel 2: specialized-wave SNN core, CH=64, 16 waves/block, 1 block/batch.
// iter k (one barrier at top, parity dbuf; NCH=64, 69 iterations total):
//   waves 0-12: C1(k) [16 idx loads], C2(k-2) [24 idx loads], C3(k-4) DPP
//   wave 13:    scan1(k-1): C1 -> LIF1 -> IDX1/S1R (mbcnt scatter)
//   wave 14:    scan2(k-3) -> S2; scan3(k-5) -> out
//   wave 15:    IDX0(k+1) from global masks
// Task bodies verbatim from passing round 10; only strides changed for CH=64.
// ---------------------------------------------------------------------------
__global__ __launch_bounds__(NTHR, 1) void snn_core13(
    const uint32_t* __restrict__ masks, const f32x2* __restrict__ w1t,
    const f32x2* __restrict__ w2t, const float* __restrict__ b1,
    const float* __restrict__ b2, const float* __restrict__ W3,
    const float* __restrict__ b3, float* __restrict__ out) {
  __shared__ f32x2 C1b[2][CH][64];                    // 64 KB
  __shared__ f32x2 C2b[2][CH][64];                    // 64 KB
  __shared__ f32x2 C3b[2][CH];                        // 1 KB
  __shared__ __align__(16) u64 S2[2][CH][2];          // 2 KB
  __shared__ __align__(16) uint32_t IDX0[2][CH][16];  // 8 KB w1t offsets
  __shared__ __align__(16) uint32_t IDX1[2][CH][24];  // 12 KB w2t offsets
  __shared__ __align__(16) u64 S1R[2][CH][2];         // 2 KB spk1 residuals
  // total ~153 KB < 160 KB -> 1 block/CU (unchanged)

  const int tid = threadIdx.x;
  const int lane = tid & 63;
  const int wv = tid >> 6;
  const int b = blockIdx.x;
  const uint32_t lane8 = (uint32_t)lane * 8u;

  const f32x2 bias1 = {b1[lane], b1[64 + lane]};
  const f32x2 bias2 = {b2[lane], b2[64 + lane]};
  const float w30a = W3[lane], w30b = W3[64 + lane];
  const float w31a = W3[128 + lane], w31b = W3[192 + lane];
  const float b30 = b3[0], b31 = b3[1];
  float m1a = 0.f, m1b = 0.f, m2a = 0.f, m2b = 0.f, m3x = 0.f, m3y = 0.f;
  float2* outv = (float2*)out;
  const uint32_t* mrow = masks + (size_t)b * TT;

  const uint32_t idx0b = lds_addr32(&IDX0[0][0][0]);
  const uint32_t idx1b = lds_addr32(&IDX1[0][0][0]);
  const uint32_t s1rb = lds_addr32(&S1R[0][0][0]);

// IDX0 builder (wave 15): chunk KK's 64 masks read coalesced from global
// (one per lane) + readlane per step; mbcnt rank scatter into sentinel-
// prefilled 16-slot lists. Sentinel 16384 = row 32 of w1t (zeros).
#define IDX0_BUILD(KK)                                                        \
  if ((KK) >= 0 && (KK) < NCH) {                                              \
    const uint32_t p0_ = idx0b + (uint32_t)(((KK) & 1) * (CH * 64));          \
    uint32_t mm_ = mrow[(KK)*CH + lane];                                      \
    _Pragma("unroll") for (int i = 0; i < CH; ++i) {                          \
      uint32_t mk_ = (uint32_t)__builtin_amdgcn_readlane((int)mm_, i);        \
      uint32_t ib_ = p0_ + (uint32_t)(i * 64);                                \
      if (lane < 16) { DSW32(ib_ + (uint32_t)lane * 4u, 16384u); }            \
      uint32_t r_ = __builtin_amdgcn_mbcnt_lo(mk_, 0u);                       \
      bool bt_ = (((u64)mk_ >> lane) & 1) != 0;                               \
      if (bt_) { DSW32(ib_ + r_ * 4u, (uint32_t)lane << 9); }                 \
    }                                                                         \
    WAIT_LGKM(0);                                                             \
  }

  __syncthreads();
  if (wv == 15) IDX0_BUILD(0);  // prime chunk 0 (published by loop-top barrier)

// ---- producer tasks (verbatim round-10 bodies, CH=64 strides) ----
#define LD4_W1(Q, S0)                                                         \
  B[S0] = glb_load_b64(Q.x + lane8, w1t);                                     \
  B[S0 + 1] = glb_load_b64(Q.y + lane8, w1t);                                 \
  B[S0 + 2] = glb_load_b64(Q.z + lane8, w1t);                                 \
  B[S0 + 3] = glb_load_b64(Q.w + lane8, w1t);
#define LD4_W2(Q, S0)                                                         \
  B[S0] = glb_load_b64(Q.x + lane8, w2t);                                     \
  B[S0 + 1] = glb_load_b64(Q.y + lane8, w2t);                                 \
  B[S0 + 2] = glb_load_b64(Q.z + lane8, w2t);                                 \
  B[S0 + 3] = glb_load_b64(Q.w + lane8, w2t);
#define C1_TASK(TASK)                                                         \
  {                                                                           \
    uint32_t ib_ = idx0b + (uint32_t)((k & 1) * (CH * 64)) + (uint32_t)((TASK)*64); \
    u32x4 q0_, q1_, q2_, q3_;                                                 \
    DSR128(q0_, ib_, 0);                                                      \
    DSR128(q1_, ib_, 16);                                                     \
    DSR128(q2_, ib_, 32);                                                     \
    DSR128(q3_, ib_, 48);                                                     \
    WAIT_LGKM(0);                                                             \
    f32x2 B[16];                                                              \
    LD4_W1(q0_, 0) LD4_W1(q1_, 4) LD4_W1(q2_, 8) LD4_W1(q3_, 12)              \
    WAIT_VM(0);                                                               \
    f32x2 c_ = {0.f, 0.f};                                                    \
    _Pragma("unroll") for (int s = 0; s < 16; ++s) c_ = pk_add(c_, B[s]);     \
    c_ = pk_add(c_, bias1);                                                   \
    C1b[k & 1][(TASK)][lane] = c_;                                            \
  }
#define C2_TASK(TASK, C2Q)                                                    \
  {                                                                           \
    uint32_t ib_ = idx1b + (uint32_t)(((C2Q)&1) * (CH * 96)) +                \
                   (uint32_t)((TASK)*96);                                     \
    uint32_t rq_ = s1rb + (uint32_t)(((C2Q)&1) * (CH * 16)) +                 \
                   (uint32_t)((TASK)*16);                                     \
    u32x4 q0_, q1_, q2_, q3_, q4_, q5_, qr_;                                  \
    DSR128(q0_, ib_, 0);                                                      \
    DSR128(q1_, ib_, 16);                                                     \
    DSR128(q2_, ib_, 32);                                                     \
    DSR128(q3_, ib_, 48);                                                     \
    DSR128(q4_, ib_, 64);                                                     \
    DSR128(q5_, ib_, 80);                                                     \
    DSR128(qr_, rq_, 0);                                                      \
    WAIT_LGKM(0);                                                             \
    f32x2 B[24];                                                              \
    LD4_W2(q0_, 0) LD4_W2(q1_, 4) LD4_W2(q2_, 8)                              \
    LD4_W2(q3_, 12) LD4_W2(q4_, 16) LD4_W2(q5_, 20)                           \
    u64 ta_ = (u64)qr_.x | ((u64)qr_.y << 32);                                \
    u64 tb_ = (u64)qr_.z | ((u64)qr_.w << 32);                                \
    WAIT_VM(0);                                                               \
    f32x2 c_ = {0.f, 0.f};                                                    \
    _Pragma("unroll") for (int s = 0; s < 24; ++s) c_ = pk_add(c_, B[s]);     \
    while (ta_) { /* rare >24-spike tails: exact ascending order */           \
      uint32_t j_ = (uint32_t)__builtin_ctzll(ta_);                           \
      ta_ &= ta_ - 1;                                                         \
      f32x2 tw_ = glb_load_b64((j_ << 9) + lane8, w2t);                       \
      WAIT_VM(0);                                                             \
      c_ = pk_add(c_, tw_);                                                   \
    }                                                                         \
    while (tb_) {                                                             \
      uint32_t j_ = 64u + (uint32_t)__builtin_ctzll(tb_);                     \
      tb_ &= tb_ - 1;                                                         \
      f32x2 tw_ = glb_load_b64((j_ << 9) + lane8, w2t);                       \
      WAIT_VM(0);                                                             \
      c_ = pk_add(c_, tw_);                                                   \
    }                                                                         \
    c_ = pk_add(c_, bias2);                                                   \
    C2b[(C2Q)&1][(TASK)][lane] = c_;                                          \
  }
#define C3_TASK(T3)                                                           \
  {                                                                           \
    int c3_ = k - 4;                                                          \
    if (c3_ >= 0 && c3_ < NCH) {                                              \
      u64 a_ = rfl64(S2[c3_ & 1][(T3)][0]);                                   \
      u64 b_ = rfl64(S2[c3_ & 1][(T3)][1]);                                   \
      float v0 = (((a_ >> lane) & 1) ? w30a : 0.f) +                          \
                 (((b_ >> lane) & 1) ? w30b : 0.f);                           \
      float v1 = (((a_ >> lane) & 1) ? w31a : 0.f) +                          \
                 (((b_ >> lane) & 1) ? w31b : 0.f);                           \
      float r0 = wave_red_add63(v0);                                          \
      float r1 = wave_red_add63(v1);                                          \
      if (lane == 63) C3b[c3_ & 1][(T3)] = f32x2{r0 + b30, r1 + b31};         \
    }                                                                         \
  }

// ---- scan helpers: 16-wide issue groups, 4 groups per 64-step chunk ----
#define ISSUE16_512(ARR, A)                                                   \
  {                                                                           \
    DSR64(ARR[0], A, 0);     DSR64(ARR[1], A, 512);                           \
    DSR64(ARR[2], A, 1024);  DSR64(ARR[3], A, 1536);                          \
    DSR64(ARR[4], A, 2048);  DSR64(ARR[5], A, 2560);                          \
    DSR64(ARR[6], A, 3072);  DSR64(ARR[7], A, 3584);                          \
    DSR64(ARR[8], A, 4096);  DSR64(ARR[9], A, 4608);                          \
    DSR64(ARR[10], A, 5120); DSR64(ARR[11], A, 5632);                         \
    DSR64(ARR[12], A, 6144); DSR64(ARR[13], A, 6656);                         \
    DSR64(ARR[14], A, 7168); DSR64(ARR[15], A, 7680);                         \
  }
#define ISSUE16_8(ARR, A)                                                     \
  {                                                                           \
    DSR64(ARR[0], A, 0);   DSR64(ARR[1], A, 8);                               \
    DSR64(ARR[2], A, 16);  DSR64(ARR[3], A, 24);                              \
    DSR64(ARR[4], A, 32);  DSR64(ARR[5], A, 40);                              \
    DSR64(ARR[6], A, 48);  DSR64(ARR[7], A, 56);                              \
    DSR64(ARR[8], A, 64);  DSR64(ARR[9], A, 72);                              \
    DSR64(ARR[10], A, 80); DSR64(ARR[11], A, 88);                             \
    DSR64(ARR[12], A, 96); DSR64(ARR[13], A, 104);                            \
    DSR64(ARR[14], A, 112); DSR64(ARR[15], A, 120);                           \
  }
// scan1 group: 16 LIF1 steps + mbcnt scatter into IDX1/S1R (round-10 body).
#define SCAN1_G(P1, PR, TB)                                                   \
  _Pragma("unroll") for (int i = 0; i < 16; ++i) {                            \
    f32x2 cv_ = arr_[i];                                                      \
    float n0_ = __fadd_rn(__fmul_rn(0.9f, m1a), cv_.x);                       \
    float n1_ = __fadd_rn(__fmul_rn(0.9f, m1b), cv_.y);                       \
    m1a = (m1a > 1.f) ? (n0_ - 1.f) : n0_;                                    \
    m1b = (m1b > 1.f) ? (n1_ - 1.f) : n1_;                                    \
    u64 s0_ = __ballot(m1a > 1.f);                                            \
    u64 s1_ = __ballot(m1b > 1.f);                                            \
    uint32_t ib_ = (P1) + (uint32_t)(((TB) + i) * 96);                        \
    if (lane < 24) { DSW32(ib_ + (uint32_t)lane * 4u, 65536u); }              \
    uint32_t r0_ = mbcnt64(s0_);                                              \
    bool b0_ = ((s0_ >> lane) & 1) != 0;                                      \
    if (b0_ && r0_ < 24u) { DSW32(ib_ + r0_ * 4u, (uint32_t)lane << 9); }     \
    uint32_t c0_ = (uint32_t)__builtin_popcountll(s0_);                       \
    uint32_t r1_ = c0_ + mbcnt64(s1_);                                        \
    bool b1_ = ((s1_ >> lane) & 1) != 0;                                      \
    if (b1_ && r1_ < 24u) {                                                   \
      DSW32(ib_ + r1_ * 4u, (uint32_t)(64 + lane) << 9);                      \
    }                                                                         \
    u64 e0_ = __ballot(b0_ && r0_ >= 24u);                                    \
    u64 e1_ = __ballot(b1_ && r1_ >= 24u);                                    \
    if (lane == 0) {                                                          \
      DSW64((PR) + (uint32_t)(((TB) + i) * 16), e0_);                         \
      DSW64((PR) + (uint32_t)(((TB) + i) * 16 + 8), e1_);                     \
    }                                                                         \
  }
#define SCAN1(CHK)                                                            \
  {                                                                           \
    const int par_ = (CHK) & 1;                                               \
    const uint32_t rb_ = lds_addr32(&C1b[par_][0][0]) + lane8;                \
    const uint32_t p1_ = idx1b + (uint32_t)(par_ * (CH * 96));                \
    const uint32_t pr_ = s1rb + (uint32_t)(par_ * (CH * 16));                 \
    f32x2 arr_[16];                                                           \
    ISSUE16_512(arr_, rb_);                                                   \
    WAIT_LGKM(0);                                                             \
    SCAN1_G(p1_, pr_, 0)                                                      \
    ISSUE16_512(arr_, (rb_ + 8192u));                                         \
    WAIT_LGKM(0);                                                             \
    SCAN1_G(p1_, pr_, 16)                                                     \
    ISSUE16_512(arr_, (rb_ + 16384u));                                        \
    WAIT_LGKM(0);                                                             \
    SCAN1_G(p1_, pr_, 32)                                                     \
    ISSUE16_512(arr_, (rb_ + 24576u));                                        \
    WAIT_LGKM(0);                                                             \
    SCAN1_G(p1_, pr_, 48)                                                     \
    WAIT_LGKM(0);                                                             \
  }
#define SCAN2_G(SB, TB)                                                       \
  _Pragma("unroll") for (int i = 0; i < 16; ++i) {                            \
    f32x2 cv_ = arr_[i];                                                      \
    float n0_ = __fadd_rn(__fmul_rn(0.9f, m2a), cv_.x);                       \
    float n1_ = __fadd_rn(__fmul_rn(0.9f, m2b), cv_.y);                       \
    m2a = (m2a > 1.f) ? (n0_ - 1.f) : n0_;                                    \
    m2b = (m2b > 1.f) ? (n1_ - 1.f) : n1_;                                    \
    u64 s0_ = __ballot(m2a > 1.f);                                            \
    u64 s1_ = __ballot(m2b > 1.f);                                            \
    if (lane == 0)                                                            \
      ds_write_b128_at((SB) + (uint32_t)(((TB) + i) * 16),                    \
                       u32x4{(uint32_t)s0_, (uint32_t)(s0_ >> 32),            \
                             (uint32_t)s1_, (uint32_t)(s1_ >> 32)});          \
  }
#define SCAN2(CHK)                                                            \
  {                                                                           \
    const int par_ = (CHK) & 1;                                               \
    const uint32_t rb_ = lds_addr32(&C2b[par_][0][0]) + lane8;                \
    const uint32_t sb_ = lds_addr32(&S2[par_][0][0]);                         \
    f32x2 arr_[16];                                                           \
    ISSUE16_512(arr_, rb_);                                                   \
    WAIT_LGKM(0);                                                             \
    SCAN2_G(sb_, 0)                                                           \
    ISSUE16_512(arr_, (rb_ + 8192u));                                         \
    WAIT_LGKM(0);                                                             \
    SCAN2_G(sb_, 16)                                                          \
    ISSUE16_512(arr_, (rb_ + 16384u));                                        \
    WAIT_LGKM(0);                                                             \
    SCAN2_G(sb_, 32)                                                          \
    ISSUE16_512(arr_, (rb_ + 24576u));                                        \
    WAIT_LGKM(0);                                                             \
    SCAN2_G(sb_, 48)                                                          \
    WAIT_LGKM(0);                                                             \
  }
#define SCAN3_G(CHK, TB)                                                      \
  _Pragma("unroll") for (int i = 0; i < 16; ++i) {                            \
    f32x2 c3_ = arr_[i];                                                      \
    float e0_ = __fadd_rn(__fmul_rn(0.9f, m3x), c3_.x);                       \
    float e1_ = __fadd_rn(__fmul_rn(0.9f, m3y), c3_.y);                       \
    m3x = (m3x > 1.f) ? (e0_ - 1.f) : e0_;                                    \
    m3y = (m3y > 1.f) ? (e1_ - 1.f) : e1_;                                    \
    if (lane == 0)                                                            \
      outv[(size_t)((CHK)*CH + (TB) + i) * BB + b] = make_float2(m3x, m3y);   \
  }
#define SCAN3(CHK)                                                            \
  {                                                                           \
    const int par_ = (CHK) & 1;                                               \
    const uint32_t cb_ = lds_addr32(&C3b[par_][0]);                           \
    f32x2 arr_[16];                                                           \
    ISSUE16_8(arr_, cb_);                                                     \
    WAIT_LGKM(0);                                                             \
    SCAN3_G(CHK, 0)                                                           \
    ISSUE16_8(arr_, (cb_ + 128u));                                            \
    WAIT_LGKM(0);                                                             \
    SCAN3_G(CHK, 16)                                                          \
    ISSUE16_8(arr_, (cb_ + 256u));                                            \
    WAIT_LGKM(0);                                                             \
    SCAN3_G(CHK, 32)                                                          \
    ISSUE16_8(arr_, (cb_ + 384u));                                            \
    WAIT_LGKM(0);                                                             \
    SCAN3_G(CHK, 48)                                                          \
  }

  // ================= chunk-synchronous main pipeline =================
  for (int k = 0; k < NCH + 5; ++k) {
    __syncthreads();
    if (wv < NPROD) {
      // tasks 0..63 = C1(chunk k), 64..127 = C2(chunk k-2); skip o-o-range.
      for (int ti = wv; ti < 2 * CH; ti += NPROD) {
        if (ti < CH) {
          if (k < NCH) C1_TASK(ti);
        } else {
          int c2q = k - 2;
          if (c2q >= 0 && c2q < NCH) C2_TASK(ti - CH, c2q);
        }
      }
      for (int t3 = wv; t3 < CH; t3 += NPROD) {
        C3_TASK(t3);
      }
    } else if (wv == 13) {
      if (k >= 1 && k - 1 < NCH) SCAN1(k - 1);
    } else if (wv == 14) {
      if (k >= 3 && k - 3 < NCH) SCAN2(k - 3);
      if (k >= 5 && k - 5 < NCH) SCAN3(k - 5);
    } else {
      IDX0_BUILD(k + 1);
    }
  }
#undef SCAN3
#undef SCAN3_G
#undef SCAN2
#undef SCAN2_G
#undef SCAN1
#undef SCAN1_G
#undef ISSUE16_8
#undef ISSUE16_512
#undef C3_TASK
#undef C2_TASK
#undef C1_TASK
#undef LD4_W2
#undef LD4_W1
#undef IDX0_BUILD
}

extern "C" void kernel_launch(void* const* d_in, const int* in_sizes, int n_in,
                              void* d_out, int out_size, void* d_ws,
                              size_t ws_size, hipStream_t stream) {
  const float* x = (const float*)d_in[0];
  const float* W1 = (const float*)d_in[1];
  const float* b1 = (const float*)d_in[2];
  const float* W2 = (const float*)d_in[3];
  const float* b2 = (const float*)d_in[4];
  const float* W3 = (const float*)d_in[5];
  const float* b3 = (const float*)d_in[6];
  float* out = (float*)d_out;

  uint32_t* masks = (uint32_t*)d_ws;                         // 4 MiB
  char* wbase = (char*)d_ws + (size_t)BB * TT * 4;
  f32x2* w1t = (f32x2*)wbase;                                // 32768 B
  f32x2* w2t = (f32x2*)(wbase + 32768);                      // 66048 B

  snn_prep<<<1, 64, 0, stream>>>(W1, W2, w1t, w2t);
  snn_encode<<<BB / 4, 64, 0, stream>>>(x, masks);
  snn_core13<<<BB, NTHR, 0, stream>>>(masks, w1t, w2t, b1, b2, W3, b3, out);
}

// Round 15
// 1306.388 us; speedup vs baseline: 1.3525x; 1.2116x over previous
//
#include <hip/hip_runtime.h>
#include <cstdint>

#define BB 256
#define TT 4096
#define FDIM 16
#define HH 128
#define CH 64           // timesteps per chunk
#define NCH (TT / CH)   // 64 chunks
#define NPROD 13        // waves 0-12 producers; 13=scan1, 14=scan2+3, 15=IDX0
#define NTHR 1024

typedef unsigned long long u64;
typedef float f32x2 __attribute__((ext_vector_type(2)));
typedef uint32_t u32x4 __attribute__((ext_vector_type(4)));

// ---------------------------------------------------------------------------
// asm helpers. SAFETY RULES (rounds 9+14 failures):
//  (1) keep task live-sets well under the 128-VGPR cap;
//  (2) asm-load buffer arrays are written UNCONDITIONALLY, straight-line,
//      between issue and wait — no branches around asm-load groups.
// Counted vmcnt waits are conservative-correct: intervening WAIT_VM(0)
// drains only make later counted waits wait for less that is still landed.
// ---------------------------------------------------------------------------
__device__ __forceinline__ uint32_t lds_addr32(const void* p) {
  return (uint32_t)(uintptr_t)p;
}
__device__ __forceinline__ f32x2 glb_load_b64(uint32_t voff, const void* base) {
  f32x2 d;
  asm volatile("global_load_dwordx2 %0, %1, %2" : "=v"(d) : "v"(voff), "s"(base));
  return d;
}
__device__ __forceinline__ void ds_write_b128_at(uint32_t addr, u32x4 v) {
  asm volatile("ds_write_b128 %0, %1" ::"v"(addr), "v"(v));
}
#define DSW32(A, D) asm volatile("ds_write_b32 %0, %1" ::"v"(A), "v"(D));
#define DSW64(A, D) asm volatile("ds_write_b64 %0, %1" ::"v"(A), "v"(D));
#define WAIT_VM(N)                                          \
  {                                                         \
    asm volatile("s_waitcnt vmcnt(" #N ")" ::: "memory");   \
    __builtin_amdgcn_sched_barrier(0);                      \
  }
#define WAIT_LGKM(N)                                        \
  {                                                         \
    asm volatile("s_waitcnt lgkmcnt(" #N ")" ::: "memory"); \
    __builtin_amdgcn_sched_barrier(0);                      \
  }
#define DSR64(D, A, OFF) \
  asm volatile("ds_read_b64 %0, %1 offset:" #OFF : "=v"(D) : "v"(A));
#define DSR128(D, A, OFF) \
  asm volatile("ds_read_b128 %0, %1 offset:" #OFF : "=v"(D) : "v"(A));
#define DS_READ_OFF(D, A, OFF) \
  asm volatile("ds_read_b32 %0, %1 offset:" #OFF : "=v"(D) : "v"(A));

// Packed fp32 add (two independent IEEE-rn adds; dataflow pins association).
__device__ __forceinline__ f32x2 pk_add(f32x2 a, f32x2 b) {
  f32x2 d;
  asm("v_pk_add_f32 %0, %1, %2" : "=v"(d) : "v"(a), "v"(b));
  return d;
}
__device__ __forceinline__ u64 rfl64(u64 x) {
  uint32_t lo = (uint32_t)__builtin_amdgcn_readfirstlane((int)(uint32_t)x);
  uint32_t hi = (uint32_t)__builtin_amdgcn_readfirstlane((int)(uint32_t)(x >> 32));
  return ((u64)hi << 32) | lo;
}
__device__ __forceinline__ uint32_t mbcnt64(u64 m) {
  uint32_t r = __builtin_amdgcn_mbcnt_lo((uint32_t)m, 0u);
  return __builtin_amdgcn_mbcnt_hi((uint32_t)(m >> 32), r);
}
// 64-lane DPP sum; result valid in lane 63 (same op sequence as rounds 1-13).
__device__ __forceinline__ float wave_red_add63(float v) {
#define DPP_ADD(c)                                                             \
  v += __int_as_float(                                                         \
      __builtin_amdgcn_update_dpp(0, __float_as_int(v), c, 0xF, 0xF, true))
  DPP_ADD(0x111);
  DPP_ADD(0x112);
  DPP_ADD(0x114);
  DPP_ADD(0x118);
  DPP_ADD(0x142);
  DPP_ADD(0x143);
#undef DPP_ADD
  return v;
}

// ---------------------------------------------------------------------------
// Kernel 0: transposed weights in workspace.
// w1t: 64 rows of 512B; rows 0..31 real, 32..63 zero (sentinels).
// w2t: 129 rows; rows 0..127 real, row 128 zero (sentinel).
// ---------------------------------------------------------------------------
__global__ __launch_bounds__(64) void snn_prep(const float* __restrict__ W1,
                                               const float* __restrict__ W2,
                                               f32x2* __restrict__ w1t,
                                               f32x2* __restrict__ w2t) {
  const int l = threadIdx.x;
  for (int j = 0; j < 64; ++j)
    w1t[j * 64 + l] = (j < 32) ? f32x2{W1[l * 32 + j], W1[(64 + l) * 32 + j]}
                               : f32x2{0.f, 0.f};
  for (int j = 0; j < 129; ++j)
    w2t[j * 64 + l] = (j < 128) ? f32x2{W2[l * 128 + j], W2[(64 + l) * 128 + j]}
                                : f32x2{0.f, 0.f};
}

// ---------------------------------------------------------------------------
// Kernel 1: delta encode -> 32-bit masks (verbatim from passing rounds 4-13).
// ---------------------------------------------------------------------------
__global__ __launch_bounds__(64) void snn_encode(const float* __restrict__ x,
                                                 uint32_t* __restrict__ masks) {
  __shared__ float tile[2][4][64][16];  // 32 KiB
  const int lane = threadIdx.x;
  const int sub = lane >> 4;
  const int f = lane & 15;
  const int b0 = blockIdx.x * 4;
  float ref = x[(size_t)(b0 + sub) * (TT * FDIM) + f];

  const float4* xv = (const float4*)x;
  float4 ld[16];
#define K1_ISSUE(G)                                                           \
  _Pragma("unroll") for (int k = 0; k < 16; ++k) {                            \
    int idx4 = k * 64 + lane;                                                 \
    int bl = idx4 >> 8;                                                       \
    int r = idx4 & 255;                                                       \
    ld[k] = xv[(size_t)(b0 + bl) * (TT * 4) + (size_t)(G) * 256 + r];         \
  }
#define K1_WRITE(BUF)                                                         \
  _Pragma("unroll") for (int k = 0; k < 16; ++k) {                            \
    int idx4 = k * 64 + lane;                                                 \
    int bl = idx4 >> 8;                                                       \
    int r = idx4 & 255;                                                       \
    ((float4*)&tile[BUF][bl][0][0])[r] = ld[k];                               \
  }
#define CHUNK_ISSUE(ARR, A)                                                   \
  {                                                                           \
    DS_READ_OFF(ARR[0], A, 0);                                                \
    DS_READ_OFF(ARR[1], A, 64);                                               \
    DS_READ_OFF(ARR[2], A, 128);                                              \
    DS_READ_OFF(ARR[3], A, 192);                                              \
    DS_READ_OFF(ARR[4], A, 256);                                              \
    DS_READ_OFF(ARR[5], A, 320);                                              \
    DS_READ_OFF(ARR[6], A, 384);                                              \
    DS_READ_OFF(ARR[7], A, 448);                                              \
  }
#define PROC8(ARR, TBASE)                                                     \
  _Pragma("unroll") for (int i = 0; i < 8; ++i) {                             \
    float cur = ARR[i];                                                       \
    float diff = cur - ref;                                                   \
    bool onb = diff >= 0.5f;                                                  \
    bool offb = diff <= -0.5f;                                                \
    u64 bon = __ballot(onb);                                                  \
    u64 boff = __ballot(offb);                                                \
    ref = (onb || offb) ? cur : ref;                                          \
    if (f == 0) {                                                             \
      uint32_t mk = (uint32_t)((bon >> (sub * 16)) & 0xFFFFull) |             \
                    ((uint32_t)((boff >> (sub * 16)) & 0xFFFFull) << 16);     \
      masks[(size_t)(b0 + sub) * TT + ((TBASE) + i)] = mk;                    \
    }                                                                         \
  }

  const uint32_t tbase =
      lds_addr32(&tile[0][0][0][0]) + (uint32_t)sub * 4096u + (uint32_t)f * 4u;

  K1_ISSUE(0);
  K1_WRITE(0);
  WAIT_LGKM(0);
  for (int g = 0; g < TT / 64; ++g) {
    if (g + 1 < TT / 64) K1_ISSUE(g + 1);
    const int buf = g & 1;
    const uint32_t caddr = tbase + (uint32_t)buf * 16384u;
    float va[8], vb[8];
    CHUNK_ISSUE(va, caddr);
#pragma unroll
    for (int c = 0; c < 8; ++c) {
      if (c < 7) {
        uint32_t an = caddr + (uint32_t)(c + 1) * 512u;
        if (c & 1) {
          CHUNK_ISSUE(va, an);
        } else {
          CHUNK_ISSUE(vb, an);
        }
        WAIT_LGKM(8);
      } else {
        WAIT_LGKM(0);
      }
      if (c & 1) {
        PROC8(vb, g * 64 + c * 8);
      } else {
        PROC8(va, g * 64 + c * 8);
      }
    }
    if (g + 1 < TT / 64) {
      K1_WRITE((g + 1) & 1);
      WAIT_LGKM(0);
    }
  }
#undef PROC8
#undef CHUNK_ISSUE
#undef K1_WRITE
#undef K1_ISSUE
}

// ---------------------------------------------------------------------------
// Kernel 2: specialized-wave SNN core, CH=64, 16 waves/block, 1 block/batch.
// Round-15 = round-13 + cross-class 2-deep producer pipeline:
//   each producer wave alternates ISSUE_C1/ISSUE_C2 with WAIT_VM(16) so 16
//   loads are always in flight; separate B1[16]/B2[16] buffers (64 VGPR),
//   all loads unconditional (sentinel-padded). IDX1 shrunk to 16 slots;
//   spike ranks >=16 go through the exact-order residual tail.
// ---------------------------------------------------------------------------
__global__ __launch_bounds__(NTHR, 1) void snn_core15(
    const uint32_t* __restrict__ masks, const f32x2* __restrict__ w1t,
    const f32x2* __restrict__ w2t, const float* __restrict__ b1,
    const float* __restrict__ b2, const float* __restrict__ W3,
    const float* __restrict__ b3, float* __restrict__ out) {
  __shared__ f32x2 C1b[2][CH][64];                    // 64 KB
  __shared__ f32x2 C2b[2][CH][64];                    // 64 KB
  __shared__ f32x2 C3b[2][CH];                        // 1 KB
  __shared__ __align__(16) u64 S2[2][CH][2];          // 2 KB
  __shared__ __align__(16) uint32_t IDX0[2][CH][16];  // 8 KB w1t offsets
  __shared__ __align__(16) uint32_t IDX1[2][CH][16];  // 8 KB w2t offsets
  __shared__ __align__(16) u64 S1R[2][CH][2];         // 2 KB spk1 residuals
  // total ~149 KB < 160 KB -> 1 block/CU

  const int tid = threadIdx.x;
  const int lane = tid & 63;
  const int wv = tid >> 6;
  const int b = blockIdx.x;
  const uint32_t lane8 = (uint32_t)lane * 8u;

  const f32x2 bias1 = {b1[lane], b1[64 + lane]};
  const f32x2 bias2 = {b2[lane], b2[64 + lane]};
  const float w30a = W3[lane], w30b = W3[64 + lane];
  const float w31a = W3[128 + lane], w31b = W3[192 + lane];
  const float b30 = b3[0], b31 = b3[1];
  float m1a = 0.f, m1b = 0.f, m2a = 0.f, m2b = 0.f, m3x = 0.f, m3y = 0.f;
  float2* outv = (float2*)out;
  const uint32_t* mrow = masks + (size_t)b * TT;

  const uint32_t idx0b = lds_addr32(&IDX0[0][0][0]);
  const uint32_t idx1b = lds_addr32(&IDX1[0][0][0]);
  const uint32_t s1rb = lds_addr32(&S1R[0][0][0]);

// IDX0 builder (wave 15): chunk KK's 64 masks read coalesced from global
// (one per lane) + readlane per step; mbcnt rank scatter into sentinel-
// prefilled 16-slot lists. Sentinel 16384 = row 32 of w1t (zeros).
#define IDX0_BUILD(KK)                                                        \
  if ((KK) >= 0 && (KK) < NCH) {                                              \
    const uint32_t p0_ = idx0b + (uint32_t)(((KK) & 1) * (CH * 64));          \
    uint32_t mm_ = mrow[(KK)*CH + lane];                                      \
    _Pragma("unroll") for (int i = 0; i < CH; ++i) {                          \
      uint32_t mk_ = (uint32_t)__builtin_amdgcn_readlane((int)mm_, i);        \
      uint32_t ib_ = p0_ + (uint32_t)(i * 64);                                \
      if (lane < 16) { DSW32(ib_ + (uint32_t)lane * 4u, 16384u); }            \
      uint32_t r_ = __builtin_amdgcn_mbcnt_lo(mk_, 0u);                       \
      bool bt_ = (((u64)mk_ >> lane) & 1) != 0;                               \
      if (bt_) { DSW32(ib_ + r_ * 4u, (uint32_t)lane << 9); }                 \
    }                                                                         \
    WAIT_LGKM(0);                                                             \
  }

  __syncthreads();
  if (wv == 15) IDX0_BUILD(0);  // prime chunk 0 (published by loop-top barrier)

// ---- producer task macros: unconditional 16-load issues, paired waits ----
#define LD4(BUF, Q, S0, W)                                                    \
  BUF[S0] = glb_load_b64(Q.x + lane8, W);                                     \
  BUF[S0 + 1] = glb_load_b64(Q.y + lane8, W);                                 \
  BUF[S0 + 2] = glb_load_b64(Q.z + lane8, W);                                 \
  BUF[S0 + 3] = glb_load_b64(Q.w + lane8, W);
#define ISSUE_C1(TASK)                                                        \
  {                                                                           \
    uint32_t ib_ = idx0b + (uint32_t)((k & 1) * (CH * 64)) + (uint32_t)((TASK)*64); \
    u32x4 q0_, q1_, q2_, q3_;                                                 \
    DSR128(q0_, ib_, 0);                                                      \
    DSR128(q1_, ib_, 16);                                                     \
    DSR128(q2_, ib_, 32);                                                     \
    DSR128(q3_, ib_, 48);                                                     \
    WAIT_LGKM(0);                                                             \
    LD4(B1, q0_, 0, w1t) LD4(B1, q1_, 4, w1t)                                 \
    LD4(B1, q2_, 8, w1t) LD4(B1, q3_, 12, w1t)                                \
  }
#define CONSUME_C1(TASK)                                                      \
  {                                                                           \
    f32x2 c_ = {0.f, 0.f};                                                    \
    _Pragma("unroll") for (int s = 0; s < 16; ++s) c_ = pk_add(c_, B1[s]);    \
    c_ = pk_add(c_, bias1);                                                   \
    C1b[k & 1][(TASK)][lane] = c_;                                            \
  }
#define ISSUE_C2(TASK, C2Q)                                                   \
  {                                                                           \
    uint32_t ib_ = idx1b + (uint32_t)(((C2Q)&1) * (CH * 64)) +                \
                   (uint32_t)((TASK)*64);                                     \
    uint32_t rq_ = s1rb + (uint32_t)(((C2Q)&1) * (CH * 16)) +                 \
                   (uint32_t)((TASK)*16);                                     \
    u32x4 q0_, q1_, q2_, q3_, qr_;                                            \
    DSR128(q0_, ib_, 0);                                                      \
    DSR128(q1_, ib_, 16);                                                     \
    DSR128(q2_, ib_, 32);                                                     \
    DSR128(q3_, ib_, 48);                                                     \
    DSR128(qr_, rq_, 0);                                                      \
    WAIT_LGKM(0);                                                             \
    LD4(B2, q0_, 0, w2t) LD4(B2, q1_, 4, w2t)                                 \
    LD4(B2, q2_, 8, w2t) LD4(B2, q3_, 12, w2t)                                \
    taP = (u64)qr_.x | ((u64)qr_.y << 32);                                    \
    tbP = (u64)qr_.z | ((u64)qr_.w << 32);                                    \
  }
#define CONSUME_C2(TASK, C2Q)                                                 \
  {                                                                           \
    f32x2 c_ = {0.f, 0.f};                                                    \
    _Pragma("unroll") for (int s = 0; s < 16; ++s) c_ = pk_add(c_, B2[s]);    \
    while (taP) { /* ranks >=16, exact ascending order; drains are safe */    \
      uint32_t j_ = (uint32_t)__builtin_ctzll(taP);                           \
      taP &= taP - 1;                                                         \
      f32x2 tw_ = glb_load_b64((j_ << 9) + lane8, w2t);                       \
      WAIT_VM(0);                                                             \
      c_ = pk_add(c_, tw_);                                                   \
    }                                                                         \
    while (tbP) {                                                             \
      uint32_t j_ = 64u + (uint32_t)__builtin_ctzll(tbP);                     \
      tbP &= tbP - 1;                                                         \
      f32x2 tw_ = glb_load_b64((j_ << 9) + lane8, w2t);                       \
      WAIT_VM(0);                                                             \
      c_ = pk_add(c_, tw_);                                                   \
    }                                                                         \
    c_ = pk_add(c_, bias2);                                                   \
    C2b[(C2Q)&1][(TASK)][lane] = c_;                                          \
  }
#define C3_TASK(T3)                                                           \
  {                                                                           \
    int c3_ = k - 4;                                                          \
    if (c3_ >= 0 && c3_ < NCH) {                                              \
      u64 a_ = rfl64(S2[c3_ & 1][(T3)][0]);                                   \
      u64 b_ = rfl64(S2[c3_ & 1][(T3)][1]);                                   \
      float v0 = (((a_ >> lane) & 1) ? w30a : 0.f) +                          \
                 (((b_ >> lane) & 1) ? w30b : 0.f);                           \
      float v1 = (((a_ >> lane) & 1) ? w31a : 0.f) +                          \
                 (((b_ >> lane) & 1) ? w31b : 0.f);                           \
      float r0 = wave_red_add63(v0);                                          \
      float r1 = wave_red_add63(v1);                                          \
      if (lane == 63) C3b[c3_ & 1][(T3)] = f32x2{r0 + b30, r1 + b31};         \
    }                                                                         \
  }

// ---- scan helpers: 16-wide issue groups, 4 groups per 64-step chunk ----
#define ISSUE16_512(ARR, A)                                                   \
  {                                                                           \
    DSR64(ARR[0], A, 0);     DSR64(ARR[1], A, 512);                           \
    DSR64(ARR[2], A, 1024);  DSR64(ARR[3], A, 1536);                          \
    DSR64(ARR[4], A, 2048);  DSR64(ARR[5], A, 2560);                          \
    DSR64(ARR[6], A, 3072);  DSR64(ARR[7], A, 3584);                          \
    DSR64(ARR[8], A, 4096);  DSR64(ARR[9], A, 4608);                          \
    DSR64(ARR[10], A, 5120); DSR64(ARR[11], A, 5632);                         \
    DSR64(ARR[12], A, 6144); DSR64(ARR[13], A, 6656);                         \
    DSR64(ARR[14], A, 7168); DSR64(ARR[15], A, 7680);                         \
  }
#define ISSUE16_8(ARR, A)                                                     \
  {                                                                           \
    DSR64(ARR[0], A, 0);   DSR64(ARR[1], A, 8);                               \
    DSR64(ARR[2], A, 16);  DSR64(ARR[3], A, 24);                              \
    DSR64(ARR[4], A, 32);  DSR64(ARR[5], A, 40);                              \
    DSR64(ARR[6], A, 48);  DSR64(ARR[7], A, 56);                              \
    DSR64(ARR[8], A, 64);  DSR64(ARR[9], A, 72);                              \
    DSR64(ARR[10], A, 80); DSR64(ARR[11], A, 88);                             \
    DSR64(ARR[12], A, 96); DSR64(ARR[13], A, 104);                            \
    DSR64(ARR[14], A, 112); DSR64(ARR[15], A, 120);                           \
  }
// scan1 group: 16 LIF1 steps + mbcnt scatter into 16-slot IDX1 + residuals.
#define SCAN1_G(P1, PR, TB)                                                   \
  _Pragma("unroll") for (int i = 0; i < 16; ++i) {                            \
    f32x2 cv_ = arr_[i];                                                      \
    float n0_ = __fadd_rn(__fmul_rn(0.9f, m1a), cv_.x);                       \
    float n1_ = __fadd_rn(__fmul_rn(0.9f, m1b), cv_.y);                       \
    m1a = (m1a > 1.f) ? (n0_ - 1.f) : n0_;                                    \
    m1b = (m1b > 1.f) ? (n1_ - 1.f) : n1_;                                    \
    u64 s0_ = __ballot(m1a > 1.f);                                            \
    u64 s1_ = __ballot(m1b > 1.f);                                            \
    uint32_t ib_ = (P1) + (uint32_t)(((TB) + i) * 64);                        \
    if (lane < 16) { DSW32(ib_ + (uint32_t)lane * 4u, 65536u); }              \
    uint32_t r0_ = mbcnt64(s0_);                                              \
    bool b0_ = ((s0_ >> lane) & 1) != 0;                                      \
    if (b0_ && r0_ < 16u) { DSW32(ib_ + r0_ * 4u, (uint32_t)lane << 9); }     \
    uint32_t c0_ = (uint32_t)__builtin_popcountll(s0_);                       \
    uint32_t r1_ = c0_ + mbcnt64(s1_);                                        \
    bool b1_ = ((s1_ >> lane) & 1) != 0;                                      \
    if (b1_ && r1_ < 16u) {                                                   \
      DSW32(ib_ + r1_ * 4u, (uint32_t)(64 + lane) << 9);                      \
    }                                                                         \
    u64 e0_ = __ballot(b0_ && r0_ >= 16u);                                    \
    u64 e1_ = __ballot(b1_ && r1_ >= 16u);                                    \
    if (lane == 0) {                                                          \
      DSW64((PR) + (uint32_t)(((TB) + i) * 16), e0_);                         \
      DSW64((PR) + (uint32_t)(((TB) + i) * 16 + 8), e1_);                     \
    }                                                                         \
  }
#define SCAN1(CHK)                                                            \
  {                                                                           \
    const int par_ = (CHK) & 1;                                               \
    const uint32_t rb_ = lds_addr32(&C1b[par_][0][0]) + lane8;                \
    const uint32_t p1_ = idx1b + (uint32_t)(par_ * (CH * 64));                \
    const uint32_t pr_ = s1rb + (uint32_t)(par_ * (CH * 16));                 \
    f32x2 arr_[16];                                                           \
    ISSUE16_512(arr_, rb_);                                                   \
    WAIT_LGKM(0);                                                             \
    SCAN1_G(p1_, pr_, 0)                                                      \
    ISSUE16_512(arr_, (rb_ + 8192u));                                         \
    WAIT_LGKM(0);                                                             \
    SCAN1_G(p1_, pr_, 16)                                                     \
    ISSUE16_512(arr_, (rb_ + 16384u));                                        \
    WAIT_LGKM(0);                                                             \
    SCAN1_G(p1_, pr_, 32)                                                     \
    ISSUE16_512(arr_, (rb_ + 24576u));                                        \
    WAIT_LGKM(0);                                                             \
    SCAN1_G(p1_, pr_, 48)                                                     \
    WAIT_LGKM(0);                                                             \
  }
#define SCAN2_G(SB, TB)                                                       \
  _Pragma("unroll") for (int i = 0; i < 16; ++i) {                            \
    f32x2 cv_ = arr_[i];                                                      \
    float n0_ = __fadd_rn(__fmul_rn(0.9f, m2a), cv_.x);                       \
    float n1_ = __fadd_rn(__fmul_rn(0.9f, m2b), cv_.y);                       \
    m2a = (m2a > 1.f) ? (n0_ - 1.f) : n0_;                                    \
    m2b = (m2b > 1.f) ? (n1_ - 1.f) : n1_;                                    \
    u64 s0_ = __ballot(m2a > 1.f);                                            \
    u64 s1_ = __ballot(m2b > 1.f);                                            \
    if (lane == 0)                                                            \
      ds_write_b128_at((SB) + (uint32_t)(((TB) + i) * 16),                    \
                       u32x4{(uint32_t)s0_, (uint32_t)(s0_ >> 32),            \
                             (uint32_t)s1_, (uint32_t)(s1_ >> 32)});          \
  }
#define SCAN2(CHK)                                                            \
  {                                                                           \
    const int par_ = (CHK) & 1;                                               \
    const uint32_t rb_ = lds_addr32(&C2b[par_][0][0]) + lane8;                \
    const uint32_t sb_ = lds_addr32(&S2[par_][0][0]);                         \
    f32x2 arr_[16];                                                           \
    ISSUE16_512(arr_, rb_);                                                   \
    WAIT_LGKM(0);                                                             \
    SCAN2_G(sb_, 0)                                                           \
    ISSUE16_512(arr_, (rb_ + 8192u));                                         \
    WAIT_LGKM(0);                                                             \
    SCAN2_G(sb_, 16)                                                          \
    ISSUE16_512(arr_, (rb_ + 16384u));                                        \
    WAIT_LGKM(0);                                                             \
    SCAN2_G(sb_, 32)                                                          \
    ISSUE16_512(arr_, (rb_ + 24576u));                                        \
    WAIT_LGKM(0);                                                             \
    SCAN2_G(sb_, 48)                                                          \
    WAIT_LGKM(0);                                                             \
  }
#define SCAN3_G(CHK, TB)                                                      \
  _Pragma("unroll") for (int i = 0; i < 16; ++i) {                            \
    f32x2 c3_ = arr_[i];                                                      \
    float e0_ = __fadd_rn(__fmul_rn(0.9f, m3x), c3_.x);                       \
    float e1_ = __fadd_rn(__fmul_rn(0.9f, m3y), c3_.y);                       \
    m3x = (m3x > 1.f) ? (e0_ - 1.f) : e0_;                                    \
    m3y = (m3y > 1.f) ? (e1_ - 1.f) : e1_;                                    \
    if (lane == 0)                                                            \
      outv[(size_t)((CHK)*CH + (TB) + i) * BB + b] = make_float2(m3x, m3y);   \
  }
#define SCAN3(CHK)                                                            \
  {                                                                           \
    const int par_ = (CHK) & 1;                                               \
    const uint32_t cb_ = lds_addr32(&C3b[par_][0]);                           \
    f32x2 arr_[16];                                                           \
    ISSUE16_8(arr_, cb_);                                                     \
    WAIT_LGKM(0);                                                             \
    SCAN3_G(CHK, 0)                                                           \
    ISSUE16_8(arr_, (cb_ + 128u));                                            \
    WAIT_LGKM(0);                                                             \
    SCAN3_G(CHK, 16)                                                          \
    ISSUE16_8(arr_, (cb_ + 256u));                                            \
    WAIT_LGKM(0);                                                             \
    SCAN3_G(CHK, 32)                                                          \
    ISSUE16_8(arr_, (cb_ + 384u));                                            \
    WAIT_LGKM(0);                                                             \
    SCAN3_G(CHK, 48)                                                          \
  }

  // ================= chunk-synchronous main pipeline =================
  for (int k = 0; k < NCH + 5; ++k) {
    __syncthreads();
    if (wv < NPROD) {
      const bool doC1 = (k < NCH);
      const int c2q = k - 2;
      const bool doC2 = (c2q >= 0) && (c2q < NCH);
      f32x2 B1[16], B2[16];
      u64 taP = 0, tbP = 0;
      if (doC1 && doC2) {
        // steady state: 2-deep cross-class pipeline, 16 loads in flight.
        int p = wv;
        ISSUE_C1(p);
        for (;;) {
          ISSUE_C2(p, c2q);
          WAIT_VM(16);        // C1(p) landed (16 newer = C2(p))
          CONSUME_C1(p);
          int pn = p + NPROD;
          if (pn < CH) {
            ISSUE_C1(pn);
            WAIT_VM(16);      // C2(p) landed (16 newer = C1(pn))
          } else {
            WAIT_VM(0);
          }
          CONSUME_C2(p, c2q); // tail drains are conservative-safe
          if (pn >= CH) break;
          p = pn;
        }
      } else if (doC1) {
        for (int p = wv; p < CH; p += NPROD) {
          ISSUE_C1(p);
          WAIT_VM(0);
          CONSUME_C1(p);
        }
      } else if (doC2) {
        for (int p = wv; p < CH; p += NPROD) {
          ISSUE_C2(p, c2q);
          WAIT_VM(0);
          CONSUME_C2(p, c2q);
        }
      }
      for (int t3 = wv; t3 < CH; t3 += NPROD) {
        C3_TASK(t3);
      }
    } else if (wv == 13) {
      if (k >= 1 && k - 1 < NCH) SCAN1(k - 1);
    } else if (wv == 14) {
      if (k >= 3 && k - 3 < NCH) SCAN2(k - 3);
      if (k >= 5 && k - 5 < NCH) SCAN3(k - 5);
    } else {
      IDX0_BUILD(k + 1);
    }
  }
#undef SCAN3
#undef SCAN3_G
#undef SCAN2
#undef SCAN2_G
#undef SCAN1
#undef SCAN1_G
#undef ISSUE16_8
#undef ISSUE16_512
#undef C3_TASK
#undef CONSUME_C2
#undef ISSUE_C2
#undef CONSUME_C1
#undef ISSUE_C1
#undef LD4
#undef IDX0_BUILD
}

extern "C" void kernel_launch(void* const* d_in, const int* in_sizes, int n_in,
                              void* d_out, int out_size, void* d_ws,
                              size_t ws_size, hipStream_t stream) {
  const float* x = (const float*)d_in[0];
  const float* W1 = (const float*)d_in[1];
  const float* b1 = (const float*)d_in[2];
  const float* W2 = (const float*)d_in[3];
  const float* b2 = (const float*)d_in[4];
  const float* W3 = (const float*)d_in[5];
  const float* b3 = (const float*)d_in[6];
  float* out = (float*)d_out;

  uint32_t* masks = (uint32_t*)d_ws;                         // 4 MiB
  char* wbase = (char*)d_ws + (size_t)BB * TT * 4;
  f32x2* w1t = (f32x2*)wbase;                                // 32768 B
  f32x2* w2t = (f32x2*)(wbase + 32768);                      // 66048 B

  snn_prep<<<1, 64, 0, stream>>>(W1, W2, w1t, w2t);
  snn_encode<<<BB / 4, 64, 0, stream>>>(x, masks);
  snn_core15<<<BB, NTHR, 0, stream>>>(masks, w1t, w2t, b1, b2, W3, b3, out);
}

// Round 16
// 1304.329 us; speedup vs baseline: 1.3546x; 1.0016x over previous
//
#include <hip/hip_runtime.h>
#include <cstdint>

#define BB 256
#define TT 4096
#define FDIM 16
#define HH 128
#define CH 64           // timesteps per chunk
#define NCH (TT / CH)   // 64 chunks
#define NPROD 13        // waves 0-12 producers; 13=scan1, 14=scan2+3, 15=IDX0
#define NTHR 1024

typedef unsigned long long u64;
typedef float f32x2 __attribute__((ext_vector_type(2)));
typedef uint32_t u32x4 __attribute__((ext_vector_type(4)));

// ---------------------------------------------------------------------------
// asm helpers. SAFETY RULES (rounds 9+14 failures):
//  (1) keep task live-sets well under the 128-VGPR cap;
//  (2) asm-load buffer arrays are written UNCONDITIONALLY, straight-line,
//      between issue and wait; conditional blocks may only gate WHOLE-buffer
//      refills that are consumed on later, equally-guarded iterations.
// Counted vmcnt waits are conservative-correct (drains only over-wait).
// ---------------------------------------------------------------------------
__device__ __forceinline__ uint32_t lds_addr32(const void* p) {
  return (uint32_t)(uintptr_t)p;
}
__device__ __forceinline__ f32x2 glb_load_b64(uint32_t voff, const void* base) {
  f32x2 d;
  asm volatile("global_load_dwordx2 %0, %1, %2" : "=v"(d) : "v"(voff), "s"(base));
  return d;
}
__device__ __forceinline__ void ds_write_b128_at(uint32_t addr, u32x4 v) {
  asm volatile("ds_write_b128 %0, %1" ::"v"(addr), "v"(v));
}
#define DSW32(A, D) asm volatile("ds_write_b32 %0, %1" ::"v"(A), "v"(D));
#define DSW64(A, D) asm volatile("ds_write_b64 %0, %1" ::"v"(A), "v"(D));
#define WAIT_VM(N)                                          \
  {                                                         \
    asm volatile("s_waitcnt vmcnt(" #N ")" ::: "memory");   \
    __builtin_amdgcn_sched_barrier(0);                      \
  }
#define WAIT_LGKM(N)                                        \
  {                                                         \
    asm volatile("s_waitcnt lgkmcnt(" #N ")" ::: "memory"); \
    __builtin_amdgcn_sched_barrier(0);                      \
  }
#define DSR64(D, A, OFF) \
  asm volatile("ds_read_b64 %0, %1 offset:" #OFF : "=v"(D) : "v"(A));
#define DSR128(D, A, OFF) \
  asm volatile("ds_read_b128 %0, %1 offset:" #OFF : "=v"(D) : "v"(A));
#define DS_READ_OFF(D, A, OFF) \
  asm volatile("ds_read_b32 %0, %1 offset:" #OFF : "=v"(D) : "v"(A));

// Packed fp32 add (two independent IEEE-rn adds; dataflow pins association).
__device__ __forceinline__ f32x2 pk_add(f32x2 a, f32x2 b) {
  f32x2 d;
  asm("v_pk_add_f32 %0, %1, %2" : "=v"(d) : "v"(a), "v"(b));
  return d;
}
__device__ __forceinline__ u64 rfl64(u64 x) {
  uint32_t lo = (uint32_t)__builtin_amdgcn_readfirstlane((int)(uint32_t)x);
  uint32_t hi = (uint32_t)__builtin_amdgcn_readfirstlane((int)(uint32_t)(x >> 32));
  return ((u64)hi << 32) | lo;
}
__device__ __forceinline__ uint32_t mbcnt64(u64 m) {
  uint32_t r = __builtin_amdgcn_mbcnt_lo((uint32_t)m, 0u);
  return __builtin_amdgcn_mbcnt_hi((uint32_t)(m >> 32), r);
}
// 64-lane DPP sum; result valid in lane 63 (same op sequence as rounds 1-15).
__device__ __forceinline__ float wave_red_add63(float v) {
#define DPP_ADD(c)                                                             \
  v += __int_as_float(                                                         \
      __builtin_amdgcn_update_dpp(0, __float_as_int(v), c, 0xF, 0xF, true))
  DPP_ADD(0x111);
  DPP_ADD(0x112);
  DPP_ADD(0x114);
  DPP_ADD(0x118);
  DPP_ADD(0x142);
  DPP_ADD(0x143);
#undef DPP_ADD
  return v;
}

// ---------------------------------------------------------------------------
// Kernel 0: transposed weights in workspace.
// w1t: 64 rows of 512B; rows 0..31 real, 32..63 zero (sentinels).
// w2t: 129 rows; rows 0..127 real, row 128 zero (sentinel).
// ---------------------------------------------------------------------------
__global__ __launch_bounds__(64) void snn_prep(const float* __restrict__ W1,
                                               const float* __restrict__ W2,
                                               f32x2* __restrict__ w1t,
                                               f32x2* __restrict__ w2t) {
  const int l = threadIdx.x;
  for (int j = 0; j < 64; ++j)
    w1t[j * 64 + l] = (j < 32) ? f32x2{W1[l * 32 + j], W1[(64 + l) * 32 + j]}
                               : f32x2{0.f, 0.f};
  for (int j = 0; j < 129; ++j)
    w2t[j * 64 + l] = (j < 128) ? f32x2{W2[l * 128 + j], W2[(64 + l) * 128 + j]}
                                : f32x2{0.f, 0.f};
}

// ---------------------------------------------------------------------------
// Kernel 1: delta encode -> 32-bit masks (verbatim from passing rounds 4-15).
// ---------------------------------------------------------------------------
__global__ __launch_bounds__(64) void snn_encode(const float* __restrict__ x,
                                                 uint32_t* __restrict__ masks) {
  __shared__ float tile[2][4][64][16];  // 32 KiB
  const int lane = threadIdx.x;
  const int sub = lane >> 4;
  const int f = lane & 15;
  const int b0 = blockIdx.x * 4;
  float ref = x[(size_t)(b0 + sub) * (TT * FDIM) + f];

  const float4* xv = (const float4*)x;
  float4 ld[16];
#define K1_ISSUE(G)                                                           \
  _Pragma("unroll") for (int k = 0; k < 16; ++k) {                            \
    int idx4 = k * 64 + lane;                                                 \
    int bl = idx4 >> 8;                                                       \
    int r = idx4 & 255;                                                       \
    ld[k] = xv[(size_t)(b0 + bl) * (TT * 4) + (size_t)(G) * 256 + r];         \
  }
#define K1_WRITE(BUF)                                                         \
  _Pragma("unroll") for (int k = 0; k < 16; ++k) {                            \
    int idx4 = k * 64 + lane;                                                 \
    int bl = idx4 >> 8;                                                       \
    int r = idx4 & 255;                                                       \
    ((float4*)&tile[BUF][bl][0][0])[r] = ld[k];                               \
  }
#define CHUNK_ISSUE(ARR, A)                                                   \
  {                                                                           \
    DS_READ_OFF(ARR[0], A, 0);                                                \
    DS_READ_OFF(ARR[1], A, 64);                                               \
    DS_READ_OFF(ARR[2], A, 128);                                              \
    DS_READ_OFF(ARR[3], A, 192);                                              \
    DS_READ_OFF(ARR[4], A, 256);                                              \
    DS_READ_OFF(ARR[5], A, 320);                                              \
    DS_READ_OFF(ARR[6], A, 384);                                              \
    DS_READ_OFF(ARR[7], A, 448);                                              \
  }
#define PROC8(ARR, TBASE)                                                     \
  _Pragma("unroll") for (int i = 0; i < 8; ++i) {                             \
    float cur = ARR[i];                                                       \
    float diff = cur - ref;                                                   \
    bool onb = diff >= 0.5f;                                                  \
    bool offb = diff <= -0.5f;                                                \
    u64 bon = __ballot(onb);                                                  \
    u64 boff = __ballot(offb);                                                \
    ref = (onb || offb) ? cur : ref;                                          \
    if (f == 0) {                                                             \
      uint32_t mk = (uint32_t)((bon >> (sub * 16)) & 0xFFFFull) |             \
                    ((uint32_t)((boff >> (sub * 16)) & 0xFFFFull) << 16);     \
      masks[(size_t)(b0 + sub) * TT + ((TBASE) + i)] = mk;                    \
    }                                                                         \
  }

  const uint32_t tbase =
      lds_addr32(&tile[0][0][0][0]) + (uint32_t)sub * 4096u + (uint32_t)f * 4u;

  K1_ISSUE(0);
  K1_WRITE(0);
  WAIT_LGKM(0);
  for (int g = 0; g < TT / 64; ++g) {
    if (g + 1 < TT / 64) K1_ISSUE(g + 1);
    const int buf = g & 1;
    const uint32_t caddr = tbase + (uint32_t)buf * 16384u;
    float va[8], vb[8];
    CHUNK_ISSUE(va, caddr);
#pragma unroll
    for (int c = 0; c < 8; ++c) {
      if (c < 7) {
        uint32_t an = caddr + (uint32_t)(c + 1) * 512u;
        if (c & 1) {
          CHUNK_ISSUE(va, an);
        } else {
          CHUNK_ISSUE(vb, an);
        }
        WAIT_LGKM(8);
      } else {
        WAIT_LGKM(0);
      }
      if (c & 1) {
        PROC8(vb, g * 64 + c * 8);
      } else {
        PROC8(va, g * 64 + c * 8);
      }
    }
    if (g + 1 < TT / 64) {
      K1_WRITE((g + 1) & 1);
      WAIT_LGKM(0);
    }
  }
#undef PROC8
#undef CHUNK_ISSUE
#undef K1_WRITE
#undef K1_ISSUE
}

// ---------------------------------------------------------------------------
// Kernel 2: specialized-wave SNN core, CH=64, 16 waves/block, 1 block/batch.
// Round-16 = round-15 with the producer pipeline deepened to 4 half-tasks
// (32 loads in flight, issue->consume distance ~2 full tasks) at the SAME
// register footprint (4 buffers x 8 slots = R15's 2 x 16).
// ---------------------------------------------------------------------------
__global__ __launch_bounds__(NTHR, 1) void snn_core16(
    const uint32_t* __restrict__ masks, const f32x2* __restrict__ w1t,
    const f32x2* __restrict__ w2t, const float* __restrict__ b1,
    const float* __restrict__ b2, const float* __restrict__ W3,
    const float* __restrict__ b3, float* __restrict__ out) {
  __shared__ f32x2 C1b[2][CH][64];                    // 64 KB
  __shared__ f32x2 C2b[2][CH][64];                    // 64 KB
  __shared__ f32x2 C3b[2][CH];                        // 1 KB
  __shared__ __align__(16) u64 S2[2][CH][2];          // 2 KB
  __shared__ __align__(16) uint32_t IDX0[2][CH][16];  // 8 KB w1t offsets
  __shared__ __align__(16) uint32_t IDX1[2][CH][16];  // 8 KB w2t offsets
  __shared__ __align__(16) u64 S1R[2][CH][2];         // 2 KB spk1 residuals
  // total ~149 KB < 160 KB -> 1 block/CU

  const int tid = threadIdx.x;
  const int lane = tid & 63;
  const int wv = tid >> 6;
  const int b = blockIdx.x;
  const uint32_t lane8 = (uint32_t)lane * 8u;

  const f32x2 bias1 = {b1[lane], b1[64 + lane]};
  const f32x2 bias2 = {b2[lane], b2[64 + lane]};
  const float w30a = W3[lane], w30b = W3[64 + lane];
  const float w31a = W3[128 + lane], w31b = W3[192 + lane];
  const float b30 = b3[0], b31 = b3[1];
  float m1a = 0.f, m1b = 0.f, m2a = 0.f, m2b = 0.f, m3x = 0.f, m3y = 0.f;
  float2* outv = (float2*)out;
  const uint32_t* mrow = masks + (size_t)b * TT;

  const uint32_t idx0b = lds_addr32(&IDX0[0][0][0]);
  const uint32_t idx1b = lds_addr32(&IDX1[0][0][0]);
  const uint32_t s1rb = lds_addr32(&S1R[0][0][0]);

// IDX0 builder (wave 15): chunk KK's 64 masks read coalesced from global
// (one per lane) + readlane per step; mbcnt rank scatter into sentinel-
// prefilled 16-slot lists. Sentinel 16384 = row 32 of w1t (zeros).
#define IDX0_BUILD(KK)                                                        \
  if ((KK) >= 0 && (KK) < NCH) {                                              \
    const uint32_t p0_ = idx0b + (uint32_t)(((KK) & 1) * (CH * 64));          \
    uint32_t mm_ = mrow[(KK)*CH + lane];                                      \
    _Pragma("unroll") for (int i = 0; i < CH; ++i) {                          \
      uint32_t mk_ = (uint32_t)__builtin_amdgcn_readlane((int)mm_, i);        \
      uint32_t ib_ = p0_ + (uint32_t)(i * 64);                                \
      if (lane < 16) { DSW32(ib_ + (uint32_t)lane * 4u, 16384u); }            \
      uint32_t r_ = __builtin_amdgcn_mbcnt_lo(mk_, 0u);                       \
      bool bt_ = (((u64)mk_ >> lane) & 1) != 0;                               \
      if (bt_) { DSW32(ib_ + r_ * 4u, (uint32_t)lane << 9); }                 \
    }                                                                         \
    WAIT_LGKM(0);                                                             \
  }

  __syncthreads();
  if (wv == 15) IDX0_BUILD(0);  // prime chunk 0 (published by loop-top barrier)

// ---- producer half-task macros: 8 unconditional loads per issue ----
#define LD4(BUF, Q, S0, W)                                                    \
  BUF[S0] = glb_load_b64(Q.x + lane8, W);                                     \
  BUF[S0 + 1] = glb_load_b64(Q.y + lane8, W);                                 \
  BUF[S0 + 2] = glb_load_b64(Q.z + lane8, W);                                 \
  BUF[S0 + 3] = glb_load_b64(Q.w + lane8, W);
#define ISS_C1H0(P, BUF)                                                      \
  {                                                                           \
    uint32_t ib_ = idx0b + (uint32_t)((k & 1) * (CH * 64)) + (uint32_t)((P)*64); \
    u32x4 qa_, qb_;                                                           \
    DSR128(qa_, ib_, 0);                                                      \
    DSR128(qb_, ib_, 16);                                                     \
    WAIT_LGKM(0);                                                             \
    LD4(BUF, qa_, 0, w1t) LD4(BUF, qb_, 4, w1t)                               \
  }
#define ISS_C1H1(P, BUF)                                                      \
  {                                                                           \
    uint32_t ib_ = idx0b + (uint32_t)((k & 1) * (CH * 64)) + (uint32_t)((P)*64); \
    u32x4 qa_, qb_;                                                           \
    DSR128(qa_, ib_, 32);                                                     \
    DSR128(qb_, ib_, 48);                                                     \
    WAIT_LGKM(0);                                                             \
    LD4(BUF, qa_, 0, w1t) LD4(BUF, qb_, 4, w1t)                               \
  }
#define ISS_C2H0(P, C2Q, BUF)                                                 \
  {                                                                           \
    uint32_t ib_ = idx1b + (uint32_t)(((C2Q)&1) * (CH * 64)) + (uint32_t)((P)*64); \
    u32x4 qa_, qb_;                                                           \
    DSR128(qa_, ib_, 0);                                                      \
    DSR128(qb_, ib_, 16);                                                     \
    WAIT_LGKM(0);                                                             \
    LD4(BUF, qa_, 0, w2t) LD4(BUF, qb_, 4, w2t)                               \
  }
#define ISS_C2H1(P, C2Q, BUF)                                                 \
  {                                                                           \
    uint32_t ib_ = idx1b + (uint32_t)(((C2Q)&1) * (CH * 64)) + (uint32_t)((P)*64); \
    uint32_t rq_ = s1rb + (uint32_t)(((C2Q)&1) * (CH * 16)) + (uint32_t)((P)*16); \
    u32x4 qa_, qb_, qr_;                                                      \
    DSR128(qa_, ib_, 32);                                                     \
    DSR128(qb_, ib_, 48);                                                     \
    DSR128(qr_, rq_, 0);                                                      \
    WAIT_LGKM(0);                                                             \
    LD4(BUF, qa_, 0, w2t) LD4(BUF, qb_, 4, w2t)                               \
    taP = (u64)qr_.x | ((u64)qr_.y << 32);                                    \
    tbP = (u64)qr_.z | ((u64)qr_.w << 32);                                    \
  }
#define CONS8(BUF, ACC)                                                       \
  { _Pragma("unroll") for (int s = 0; s < 8; ++s) ACC = pk_add(ACC, BUF[s]); }
#define FIN_C1(P, ACC)                                                        \
  {                                                                           \
    f32x2 c_ = pk_add(ACC, bias1);                                            \
    C1b[k & 1][(P)][lane] = c_;                                               \
  }
#define FIN_C2(P, C2Q, ACC)                                                   \
  {                                                                           \
    f32x2 c_ = ACC;                                                           \
    while (taP) { /* ranks >=16, exact ascending order; drains are safe */    \
      uint32_t j_ = (uint32_t)__builtin_ctzll(taP);                           \
      taP &= taP - 1;                                                         \
      f32x2 tw_ = glb_load_b64((j_ << 9) + lane8, w2t);                       \
      WAIT_VM(0);                                                             \
      c_ = pk_add(c_, tw_);                                                   \
    }                                                                         \
    while (tbP) {                                                             \
      uint32_t j_ = 64u + (uint32_t)__builtin_ctzll(tbP);                     \
      tbP &= tbP - 1;                                                         \
      f32x2 tw_ = glb_load_b64((j_ << 9) + lane8, w2t);                       \
      WAIT_VM(0);                                                             \
      c_ = pk_add(c_, tw_);                                                   \
    }                                                                         \
    c_ = pk_add(c_, bias2);                                                   \
    C2b[(C2Q)&1][(P)][lane] = c_;                                             \
  }
#define C3_TASK(T3)                                                           \
  {                                                                           \
    int c3_ = k - 4;                                                          \
    if (c3_ >= 0 && c3_ < NCH) {                                              \
      u64 a_ = rfl64(S2[c3_ & 1][(T3)][0]);                                   \
      u64 b_ = rfl64(S2[c3_ & 1][(T3)][1]);                                   \
      float v0 = (((a_ >> lane) & 1) ? w30a : 0.f) +                          \
                 (((b_ >> lane) & 1) ? w30b : 0.f);                           \
      float v1 = (((a_ >> lane) & 1) ? w31a : 0.f) +                          \
                 (((b_ >> lane) & 1) ? w31b : 0.f);                           \
      float r0 = wave_red_add63(v0);                                          \
      float r1 = wave_red_add63(v1);                                          \
      if (lane == 63) C3b[c3_ & 1][(T3)] = f32x2{r0 + b30, r1 + b31};         \
    }                                                                         \
  }

// ---- scan helpers: 16-wide issue groups, 4 groups per 64-step chunk ----
#define ISSUE16_512(ARR, A)                                                   \
  {                                                                           \
    DSR64(ARR[0], A, 0);     DSR64(ARR[1], A, 512);                           \
    DSR64(ARR[2], A, 1024);  DSR64(ARR[3], A, 1536);                          \
    DSR64(ARR[4], A, 2048);  DSR64(ARR[5], A, 2560);                          \
    DSR64(ARR[6], A, 3072);  DSR64(ARR[7], A, 3584);                          \
    DSR64(ARR[8], A, 4096);  DSR64(ARR[9], A, 4608);                          \
    DSR64(ARR[10], A, 5120); DSR64(ARR[11], A, 5632);                         \
    DSR64(ARR[12], A, 6144); DSR64(ARR[13], A, 6656);                         \
    DSR64(ARR[14], A, 7168); DSR64(ARR[15], A, 7680);                         \
  }
#define ISSUE16_8(ARR, A)                                                     \
  {                                                                           \
    DSR64(ARR[0], A, 0);   DSR64(ARR[1], A, 8);                               \
    DSR64(ARR[2], A, 16);  DSR64(ARR[3], A, 24);                              \
    DSR64(ARR[4], A, 32);  DSR64(ARR[5], A, 40);                              \
    DSR64(ARR[6], A, 48);  DSR64(ARR[7], A, 56);                              \
    DSR64(ARR[8], A, 64);  DSR64(ARR[9], A, 72);                              \
    DSR64(ARR[10], A, 80); DSR64(ARR[11], A, 88);                             \
    DSR64(ARR[12], A, 96); DSR64(ARR[13], A, 104);                            \
    DSR64(ARR[14], A, 112); DSR64(ARR[15], A, 120);                           \
  }
// scan1 group: 16 LIF1 steps + mbcnt scatter into 16-slot IDX1 + residuals.
#define SCAN1_G(P1, PR, TB)                                                   \
  _Pragma("unroll") for (int i = 0; i < 16; ++i) {                            \
    f32x2 cv_ = arr_[i];                                                      \
    float n0_ = __fadd_rn(__fmul_rn(0.9f, m1a), cv_.x);                       \
    float n1_ = __fadd_rn(__fmul_rn(0.9f, m1b), cv_.y);                       \
    m1a = (m1a > 1.f) ? (n0_ - 1.f) : n0_;                                    \
    m1b = (m1b > 1.f) ? (n1_ - 1.f) : n1_;                                    \
    u64 s0_ = __ballot(m1a > 1.f);                                            \
    u64 s1_ = __ballot(m1b > 1.f);                                            \
    uint32_t ib_ = (P1) + (uint32_t)(((TB) + i) * 64);                        \
    if (lane < 16) { DSW32(ib_ + (uint32_t)lane * 4u, 65536u); }              \
    uint32_t r0_ = mbcnt64(s0_);                                              \
    bool b0_ = ((s0_ >> lane) & 1) != 0;                                      \
    if (b0_ && r0_ < 16u) { DSW32(ib_ + r0_ * 4u, (uint32_t)lane << 9); }     \
    uint32_t c0_ = (uint32_t)__builtin_popcountll(s0_);                       \
    uint32_t r1_ = c0_ + mbcnt64(s1_);                                        \
    bool b1_ = ((s1_ >> lane) & 1) != 0;                                      \
    if (b1_ && r1_ < 16u) {                                                   \
      DSW32(ib_ + r1_ * 4u, (uint32_t)(64 + lane) << 9);                      \
    }                                                                         \
    u64 e0_ = __ballot(b0_ && r0_ >= 16u);                                    \
    u64 e1_ = __ballot(b1_ && r1_ >= 16u);                                    \
    if (lane == 0) {                                                          \
      DSW64((PR) + (uint32_t)(((TB) + i) * 16), e0_);                         \
      DSW64((PR) + (uint32_t)(((TB) + i) * 16 + 8), e1_);                     \
    }                                                                         \
  }
#define SCAN1(CHK)                                                            \
  {                                                                           \
    const int par_ = (CHK) & 1;                                               \
    const uint32_t rb_ = lds_addr32(&C1b[par_][0][0]) + lane8;                \
    const uint32_t p1_ = idx1b + (uint32_t)(par_ * (CH * 64));                \
    const uint32_t pr_ = s1rb + (uint32_t)(par_ * (CH * 16));                 \
    f32x2 arr_[16];                                                           \
    ISSUE16_512(arr_, rb_);                                                   \
    WAIT_LGKM(0);                                                             \
    SCAN1_G(p1_, pr_, 0)                                                      \
    ISSUE16_512(arr_, (rb_ + 8192u));                                         \
    WAIT_LGKM(0);                                                             \
    SCAN1_G(p1_, pr_, 16)                                                     \
    ISSUE16_512(arr_, (rb_ + 16384u));                                        \
    WAIT_LGKM(0);                                                             \
    SCAN1_G(p1_, pr_, 32)                                                     \
    ISSUE16_512(arr_, (rb_ + 24576u));                                        \
    WAIT_LGKM(0);                                                             \
    SCAN1_G(p1_, pr_, 48)                                                     \
    WAIT_LGKM(0);                                                             \
  }
#define SCAN2_G(SB, TB)                                                       \
  _Pragma("unroll") for (int i = 0; i < 16; ++i) {                            \
    f32x2 cv_ = arr_[i];                                                      \
    float n0_ = __fadd_rn(__fmul_rn(0.9f, m2a), cv_.x);                       \
    float n1_ = __fadd_rn(__fmul_rn(0.9f, m2b), cv_.y);                       \
    m2a = (m2a > 1.f) ? (n0_ - 1.f) : n0_;                                    \
    m2b = (m2b > 1.f) ? (n1_ - 1.f) : n1_;                                    \
    u64 s0_ = __ballot(m2a > 1.f);                                            \
    u64 s1_ = __ballot(m2b > 1.f);                                            \
    if (lane == 0)                                                            \
      ds_write_b128_at((SB) + (uint32_t)(((TB) + i) * 16),                    \
                       u32x4{(uint32_t)s0_, (uint32_t)(s0_ >> 32),            \
                             (uint32_t)s1_, (uint32_t)(s1_ >> 32)});          \
  }
#define SCAN2(CHK)                                                            \
  {                                                                           \
    const int par_ = (CHK) & 1;                                               \
    const uint32_t rb_ = lds_addr32(&C2b[par_][0][0]) + lane8;                \
    const uint32_t sb_ = lds_addr32(&S2[par_][0][0]);                         \
    f32x2 arr_[16];                                                           \
    ISSUE16_512(arr_, rb_);                                                   \
    WAIT_LGKM(0);                                                             \
    SCAN2_G(sb_, 0)                                                           \
    ISSUE16_512(arr_, (rb_ + 8192u));                                         \
    WAIT_LGKM(0);                                                             \
    SCAN2_G(sb_, 16)                                                          \
    ISSUE16_512(arr_, (rb_ + 16384u));                                        \
    WAIT_LGKM(0);                                                             \
    SCAN2_G(sb_, 32)                                                          \
    ISSUE16_512(arr_, (rb_ + 24576u));                                        \
    WAIT_LGKM(0);                                                             \
    SCAN2_G(sb_, 48)                                                          \
    WAIT_LGKM(0);                                                             \
  }
#define SCAN3_G(CHK, TB)                                                      \
  _Pragma("unroll") for (int i = 0; i < 16; ++i) {                            \
    f32x2 c3_ = arr_[i];                                                      \
    float e0_ = __fadd_rn(__fmul_rn(0.9f, m3x), c3_.x);                       \
    float e1_ = __fadd_rn(__fmul_rn(0.9f, m3y), c3_.y);                       \
    m3x = (m3x > 1.f) ? (e0_ - 1.f) : e0_;                                    \
    m3y = (m3y > 1.f) ? (e1_ - 1.f) : e1_;                                    \
    if (lane == 0)                                                            \
      outv[(size_t)((CHK)*CH + (TB) + i) * BB + b] = make_float2(m3x, m3y);   \
  }
#define SCAN3(CHK)                                                            \
  {                                                                           \
    const int par_ = (CHK) & 1;                                               \
    const uint32_t cb_ = lds_addr32(&C3b[par_][0]);                           \
    f32x2 arr_[16];                                                           \
    ISSUE16_8(arr_, cb_);                                                     \
    WAIT_LGKM(0);                                                             \
    SCAN3_G(CHK, 0)                                                           \
    ISSUE16_8(arr_, (cb_ + 128u));                                            \
    WAIT_LGKM(0);                                                             \
    SCAN3_G(CHK, 16)                                                          \
    ISSUE16_8(arr_, (cb_ + 256u));                                            \
    WAIT_LGKM(0);                                                             \
    SCAN3_G(CHK, 32)                                                          \
    ISSUE16_8(arr_, (cb_ + 384u));                                            \
    WAIT_LGKM(0);                                                             \
    SCAN3_G(CHK, 48)                                                          \
  }

  // ================= chunk-synchronous main pipeline =================
  for (int k = 0; k < NCH + 5; ++k) {
    __syncthreads();
    if (wv < NPROD) {
      const bool doC1 = (k < NCH);
      const int c2q = k - 2;
      const bool doC2 = (c2q >= 0) && (c2q < NCH);
      f32x2 Ba[8], Bb[8], Bc[8], Bd[8];
      u64 taP = 0, tbP = 0;
      if (doC1 && doC2) {
        // steady state: 4-deep half-task pipeline, 32 loads in flight.
        int p = wv;
        ISS_C1H0(p, Ba);
        ISS_C1H1(p, Bb);
        ISS_C2H0(p, c2q, Bc);
        ISS_C2H1(p, c2q, Bd);
        for (;;) {
          int pn = p + NPROD;
          bool more = pn < CH;
          f32x2 acc1 = {0.f, 0.f};
          WAIT_VM(24);
          CONS8(Ba, acc1);
          if (more) { ISS_C1H0(pn, Ba); }
          if (more) { WAIT_VM(24); } else { WAIT_VM(16); }
          CONS8(Bb, acc1);
          FIN_C1(p, acc1);
          if (more) { ISS_C1H1(pn, Bb); }
          if (more) { WAIT_VM(24); } else { WAIT_VM(8); }
          f32x2 acc2 = {0.f, 0.f};
          CONS8(Bc, acc2);
          if (more) { ISS_C2H0(pn, c2q, Bc); }
          if (more) { WAIT_VM(24); } else { WAIT_VM(0); }
          CONS8(Bd, acc2);
          FIN_C2(p, c2q, acc2);  // consumes taP/tbP of p
          if (more) { ISS_C2H1(pn, c2q, Bd); }  // sets taP/tbP for pn
          if (!more) break;
          p = pn;
        }
      } else if (doC1) {
        for (int p = wv; p < CH; p += NPROD) {
          ISS_C1H0(p, Ba);
          ISS_C1H1(p, Bb);
          WAIT_VM(0);
          f32x2 acc1 = {0.f, 0.f};
          CONS8(Ba, acc1);
          CONS8(Bb, acc1);
          FIN_C1(p, acc1);
        }
      } else if (doC2) {
        for (int p = wv; p < CH; p += NPROD) {
          ISS_C2H0(p, c2q, Bc);
          ISS_C2H1(p, c2q, Bd);
          WAIT_VM(0);
          f32x2 acc2 = {0.f, 0.f};
          CONS8(Bc, acc2);
          CONS8(Bd, acc2);
          FIN_C2(p, c2q, acc2);
        }
      }
      for (int t3 = wv; t3 < CH; t3 += NPROD) {
        C3_TASK(t3);
      }
    } else if (wv == 13) {
      if (k >= 1 && k - 1 < NCH) SCAN1(k - 1);
    } else if (wv == 14) {
      if (k >= 3 && k - 3 < NCH) SCAN2(k - 3);
      if (k >= 5 && k - 5 < NCH) SCAN3(k - 5);
    } else {
      IDX0_BUILD(k + 1);
    }
  }
#undef SCAN3
#undef SCAN3_G
#undef SCAN2
#undef SCAN2_G
#undef SCAN1
#undef SCAN1_G
#undef ISSUE16_8
#undef ISSUE16_512
#undef C3_TASK
#undef FIN_C2
#undef FIN_C1
#undef CONS8
#undef ISS_C2H1
#undef ISS_C2H0
#undef ISS_C1H1
#undef ISS_C1H0
#undef LD4
#undef IDX0_BUILD
}

extern "C" void kernel_launch(void* const* d_in, const int* in_sizes, int n_in,
                              void* d_out, int out_size, void* d_ws,
                              size_t ws_size, hipStream_t stream) {
  const float* x = (const float*)d_in[0];
  const float* W1 = (const float*)d_in[1];
  const float* b1 = (const float*)d_in[2];
  const float* W2 = (const float*)d_in[3];
  const float* b2 = (const float*)d_in[4];
  const float* W3 = (const float*)d_in[5];
  const float* b3 = (const float*)d_in[6];
  float* out = (float*)d_out;

  uint32_t* masks = (uint32_t*)d_ws;                         // 4 MiB
  char* wbase = (char*)d_ws + (size_t)BB * TT * 4;
  f32x2* w1t = (f32x2*)wbase;                                // 32768 B
  f32x2* w2t = (f32x2*)(wbase + 32768);                      // 66048 B

  snn_prep<<<1, 64, 0, stream>>>(W1, W2, w1t, w2t);
  snn_encode<<<BB / 4, 64, 0, stream>>>(x, masks);
  snn_core16<<<BB, NTHR, 0, stream>>>(masks, w1t, w2t, b1, b2, W3, b3, out);
}

// Round 17
// 1165.621 us; speedup vs baseline: 1.5158x; 1.1190x over previous
//
#include <hip/hip_runtime.h>
#include <cstdint>

#define BB 256
#define TT 4096
#define FDIM 16
#define HH 128
#define CH 32           // timesteps per chunk (LDS budget with W2L)
#define NCH (TT / CH)   // 128 chunks
#define NPROD 13        // waves 0-12 producers; 13=scan1, 14=scan2+3, 15=IDX0
#define NTHR 1024

typedef unsigned long long u64;
typedef float f32x2 __attribute__((ext_vector_type(2)));
typedef uint32_t u32x4 __attribute__((ext_vector_type(4)));

// ---------------------------------------------------------------------------
// asm helpers. SAFETY RULES (rounds 9+14 failures):
//  (1) keep task live-sets well under the 128-VGPR cap;
//  (2) asm-load buffer arrays are written UNCONDITIONALLY, straight-line,
//      between issue and wait.
// vm and lgkm are separate counter domains: C1 gathers (global/vm) and C2
// gathers (LDS/lgkm) wait independently -> cross-class hiding is exact.
// ---------------------------------------------------------------------------
__device__ __forceinline__ uint32_t lds_addr32(const void* p) {
  return (uint32_t)(uintptr_t)p;
}
__device__ __forceinline__ f32x2 glb_load_b64(uint32_t voff, const void* base) {
  f32x2 d;
  asm volatile("global_load_dwordx2 %0, %1, %2" : "=v"(d) : "v"(voff), "s"(base));
  return d;
}
__device__ __forceinline__ void ds_write_b128_at(uint32_t addr, u32x4 v) {
  asm volatile("ds_write_b128 %0, %1" ::"v"(addr), "v"(v));
}
#define DSW32(A, D) asm volatile("ds_write_b32 %0, %1" ::"v"(A), "v"(D));
#define DSW64(A, D) asm volatile("ds_write_b64 %0, %1" ::"v"(A), "v"(D));
#define WAIT_VM(N)                                          \
  {                                                         \
    asm volatile("s_waitcnt vmcnt(" #N ")" ::: "memory");   \
    __builtin_amdgcn_sched_barrier(0);                      \
  }
#define WAIT_LGKM(N)                                        \
  {                                                         \
    asm volatile("s_waitcnt lgkmcnt(" #N ")" ::: "memory"); \
    __builtin_amdgcn_sched_barrier(0);                      \
  }
#define DSR64(D, A, OFF) \
  asm volatile("ds_read_b64 %0, %1 offset:" #OFF : "=v"(D) : "v"(A));
#define DSR128(D, A, OFF) \
  asm volatile("ds_read_b128 %0, %1 offset:" #OFF : "=v"(D) : "v"(A));
#define DS_READ_OFF(D, A, OFF) \
  asm volatile("ds_read_b32 %0, %1 offset:" #OFF : "=v"(D) : "v"(A));

// Packed fp32 add (two independent IEEE-rn adds; dataflow pins association).
__device__ __forceinline__ f32x2 pk_add(f32x2 a, f32x2 b) {
  f32x2 d;
  asm("v_pk_add_f32 %0, %1, %2" : "=v"(d) : "v"(a), "v"(b));
  return d;
}
__device__ __forceinline__ u64 rfl64(u64 x) {
  uint32_t lo = (uint32_t)__builtin_amdgcn_readfirstlane((int)(uint32_t)x);
  uint32_t hi = (uint32_t)__builtin_amdgcn_readfirstlane((int)(uint32_t)(x >> 32));
  return ((u64)hi << 32) | lo;
}
__device__ __forceinline__ uint32_t mbcnt64(u64 m) {
  uint32_t r = __builtin_amdgcn_mbcnt_lo((uint32_t)m, 0u);
  return __builtin_amdgcn_mbcnt_hi((uint32_t)(m >> 32), r);
}
// 64-lane DPP sum; result valid in lane 63 (same op sequence as rounds 1-16).
__device__ __forceinline__ float wave_red_add63(float v) {
#define DPP_ADD(c)                                                             \
  v += __int_as_float(                                                         \
      __builtin_amdgcn_update_dpp(0, __float_as_int(v), c, 0xF, 0xF, true))
  DPP_ADD(0x111);
  DPP_ADD(0x112);
  DPP_ADD(0x114);
  DPP_ADD(0x118);
  DPP_ADD(0x142);
  DPP_ADD(0x143);
#undef DPP_ADD
  return v;
}

// ---------------------------------------------------------------------------
// Kernel 0: transposed weights in workspace.
// w1t: 64 rows of 512B; rows 0..31 real, 32..63 zero (sentinels).
// w2t: 129 rows; rows 0..127 real, row 128 zero (sentinel).
// ---------------------------------------------------------------------------
__global__ __launch_bounds__(64) void snn_prep(const float* __restrict__ W1,
                                               const float* __restrict__ W2,
                                               f32x2* __restrict__ w1t,
                                               f32x2* __restrict__ w2t) {
  const int l = threadIdx.x;
  for (int j = 0; j < 64; ++j)
    w1t[j * 64 + l] = (j < 32) ? f32x2{W1[l * 32 + j], W1[(64 + l) * 32 + j]}
                               : f32x2{0.f, 0.f};
  for (int j = 0; j < 129; ++j)
    w2t[j * 64 + l] = (j < 128) ? f32x2{W2[l * 128 + j], W2[(64 + l) * 128 + j]}
                                : f32x2{0.f, 0.f};
}

// ---------------------------------------------------------------------------
// Kernel 1: delta encode -> 32-bit masks (verbatim from passing rounds 4-16).
// ---------------------------------------------------------------------------
__global__ __launch_bounds__(64) void snn_encode(const float* __restrict__ x,
                                                 uint32_t* __restrict__ masks) {
  __shared__ float tile[2][4][64][16];  // 32 KiB
  const int lane = threadIdx.x;
  const int sub = lane >> 4;
  const int f = lane & 15;
  const int b0 = blockIdx.x * 4;
  float ref = x[(size_t)(b0 + sub) * (TT * FDIM) + f];

  const float4* xv = (const float4*)x;
  float4 ld[16];
#define K1_ISSUE(G)                                                           \
  _Pragma("unroll") for (int k = 0; k < 16; ++k) {                            \
    int idx4 = k * 64 + lane;                                                 \
    int bl = idx4 >> 8;                                                       \
    int r = idx4 & 255;                                                       \
    ld[k] = xv[(size_t)(b0 + bl) * (TT * 4) + (size_t)(G) * 256 + r];         \
  }
#define K1_WRITE(BUF)                                                         \
  _Pragma("unroll") for (int k = 0; k < 16; ++k) {                            \
    int idx4 = k * 64 + lane;                                                 \
    int bl = idx4 >> 8;                                                       \
    int r = idx4 & 255;                                                       \
    ((float4*)&tile[BUF][bl][0][0])[r] = ld[k];                               \
  }
#define CHUNK_ISSUE(ARR, A)                                                   \
  {                                                                           \
    DS_READ_OFF(ARR[0], A, 0);                                                \
    DS_READ_OFF(ARR[1], A, 64);                                               \
    DS_READ_OFF(ARR[2], A, 128);                                              \
    DS_READ_OFF(ARR[3], A, 192);                                              \
    DS_READ_OFF(ARR[4], A, 256);                                              \
    DS_READ_OFF(ARR[5], A, 320);                                              \
    DS_READ_OFF(ARR[6], A, 384);                                              \
    DS_READ_OFF(ARR[7], A, 448);                                              \
  }
#define PROC8(ARR, TBASE)                                                     \
  _Pragma("unroll") for (int i = 0; i < 8; ++i) {                             \
    float cur = ARR[i];                                                       \
    float diff = cur - ref;                                                   \
    bool onb = diff >= 0.5f;                                                  \
    bool offb = diff <= -0.5f;                                                \
    u64 bon = __ballot(onb);                                                  \
    u64 boff = __ballot(offb);                                                \
    ref = (onb || offb) ? cur : ref;                                          \
    if (f == 0) {                                                             \
      uint32_t mk = (uint32_t)((bon >> (sub * 16)) & 0xFFFFull) |             \
                    ((uint32_t)((boff >> (sub * 16)) & 0xFFFFull) << 16);     \
      masks[(size_t)(b0 + sub) * TT + ((TBASE) + i)] = mk;                    \
    }                                                                         \
  }

  const uint32_t tbase =
      lds_addr32(&tile[0][0][0][0]) + (uint32_t)sub * 4096u + (uint32_t)f * 4u;

  K1_ISSUE(0);
  K1_WRITE(0);
  WAIT_LGKM(0);
  for (int g = 0; g < TT / 64; ++g) {
    if (g + 1 < TT / 64) K1_ISSUE(g + 1);
    const int buf = g & 1;
    const uint32_t caddr = tbase + (uint32_t)buf * 16384u;
    float va[8], vb[8];
    CHUNK_ISSUE(va, caddr);
#pragma unroll
    for (int c = 0; c < 8; ++c) {
      if (c < 7) {
        uint32_t an = caddr + (uint32_t)(c + 1) * 512u;
        if (c & 1) {
          CHUNK_ISSUE(va, an);
        } else {
          CHUNK_ISSUE(vb, an);
        }
        WAIT_LGKM(8);
      } else {
        WAIT_LGKM(0);
      }
      if (c & 1) {
        PROC8(vb, g * 64 + c * 8);
      } else {
        PROC8(va, g * 64 + c * 8);
      }
    }
    if (g + 1 < TT / 64) {
      K1_WRITE((g + 1) & 1);
      WAIT_LGKM(0);
    }
  }
#undef PROC8
#undef CHUNK_ISSUE
#undef K1_WRITE
#undef K1_ISSUE
}

// ---------------------------------------------------------------------------
// Kernel 2: specialized-wave SNN core, CH=32, 16 waves/block, 1 block/batch.
// Round-17 = round-15 structure + PIPE SPLIT: W2 staged in LDS (66 KB,
// lane-indexed 512B rows -> conflict-free ds_read_b64); per task p the C1
// global loads (vm) are issued first, the full C2 LDS task runs under their
// flight (lgkm), then vm drains and C1 is consumed. Separate counter
// domains -> exact waits, no cross-class drain.
// ---------------------------------------------------------------------------
__global__ __launch_bounds__(NTHR, 1) void snn_core17(
    const uint32_t* __restrict__ masks, const f32x2* __restrict__ w1t,
    const f32x2* __restrict__ w2t, const float* __restrict__ b1,
    const float* __restrict__ b2, const float* __restrict__ W3,
    const float* __restrict__ b3, float* __restrict__ out) {
  __shared__ __align__(16) f32x2 W2L[129 * 64];       // 66048 B (row 128 = 0)
  __shared__ f32x2 C1b[2][CH][64];                    // 32 KB
  __shared__ f32x2 C2b[2][CH][64];                    // 32 KB
  __shared__ f32x2 C3b[2][CH];                        // 512 B
  __shared__ __align__(16) u64 S2[2][CH][2];          // 1 KB
  __shared__ __align__(16) uint32_t IDX0[2][CH][16];  // 4 KB w1t offsets
  __shared__ __align__(16) uint32_t IDX1[2][CH][16];  // 4 KB W2L offsets
  __shared__ __align__(16) u64 S1R[2][CH][2];         // 1 KB spk1 residuals
  // total ~139 KB < 160 KB -> 1 block/CU

  const int tid = threadIdx.x;
  const int lane = tid & 63;
  const int wv = tid >> 6;
  const int b = blockIdx.x;
  const uint32_t lane8 = (uint32_t)lane * 8u;

  // one-time W2 stage into LDS (coalesced; includes zero sentinel row 128)
  for (int i = tid; i < 129 * 64; i += NTHR) W2L[i] = w2t[i];

  const f32x2 bias1 = {b1[lane], b1[64 + lane]};
  const f32x2 bias2 = {b2[lane], b2[64 + lane]};
  const float w30a = W3[lane], w30b = W3[64 + lane];
  const float w31a = W3[128 + lane], w31b = W3[192 + lane];
  const float b30 = b3[0], b31 = b3[1];
  float m1a = 0.f, m1b = 0.f, m2a = 0.f, m2b = 0.f, m3x = 0.f, m3y = 0.f;
  float2* outv = (float2*)out;
  const uint32_t* mrow = masks + (size_t)b * TT;

  const uint32_t idx0b = lds_addr32(&IDX0[0][0][0]);
  const uint32_t idx1b = lds_addr32(&IDX1[0][0][0]);
  const uint32_t s1rb = lds_addr32(&S1R[0][0][0]);
  const uint32_t w2lb = lds_addr32(&W2L[0]);

// IDX0 builder (wave 15): chunk KK's 32 masks read coalesced from global
// (lane&31) + readlane per step; mbcnt rank scatter into sentinel-prefilled
// 16-slot lists. Sentinel 16384 = row 32 of w1t (zeros).
#define IDX0_BUILD(KK)                                                        \
  if ((KK) >= 0 && (KK) < NCH) {                                              \
    const uint32_t p0_ = idx0b + (uint32_t)(((KK) & 1) * (CH * 64));          \
    uint32_t mm_ = mrow[(KK)*CH + (lane & 31)];                               \
    _Pragma("unroll") for (int i = 0; i < CH; ++i) {                          \
      uint32_t mk_ = (uint32_t)__builtin_amdgcn_readlane((int)mm_, i);        \
      uint32_t ib_ = p0_ + (uint32_t)(i * 64);                                \
      if (lane < 16) { DSW32(ib_ + (uint32_t)lane * 4u, 16384u); }            \
      uint32_t r_ = __builtin_amdgcn_mbcnt_lo(mk_, 0u);                       \
      bool bt_ = (((u64)mk_ >> lane) & 1) != 0;                               \
      if (bt_) { DSW32(ib_ + r_ * 4u, (uint32_t)lane << 9); }                 \
    }                                                                         \
    WAIT_LGKM(0);                                                             \
  }

  __syncthreads();
  if (wv == 15) IDX0_BUILD(0);  // prime chunk 0 (published by loop-top barrier)

// ---- producer task macros ----
#define LD4G(BUF, Q, S0, W)                                                   \
  BUF[S0] = glb_load_b64(Q.x + lane8, W);                                     \
  BUF[S0 + 1] = glb_load_b64(Q.y + lane8, W);                                 \
  BUF[S0 + 2] = glb_load_b64(Q.z + lane8, W);                                 \
  BUF[S0 + 3] = glb_load_b64(Q.w + lane8, W);
#define LD4L(BUF, Q, S0)                                                      \
  DSR64(BUF[S0], w2lb + Q.x + lane8, 0);                                      \
  DSR64(BUF[S0 + 1], w2lb + Q.y + lane8, 0);                                  \
  DSR64(BUF[S0 + 2], w2lb + Q.z + lane8, 0);                                  \
  DSR64(BUF[S0 + 3], w2lb + Q.w + lane8, 0);
// C1: issue 16 global loads (vm domain).
#define ISSUE_C1(P)                                                           \
  {                                                                           \
    uint32_t ib_ = idx0b + (uint32_t)((k & 1) * (CH * 64)) + (uint32_t)((P)*64); \
    u32x4 q0_, q1_, q2_, q3_;                                                 \
    DSR128(q0_, ib_, 0);                                                      \
    DSR128(q1_, ib_, 16);                                                     \
    DSR128(q2_, ib_, 32);                                                     \
    DSR128(q3_, ib_, 48);                                                     \
    WAIT_LGKM(0);                                                             \
    LD4G(B1, q0_, 0, w1t) LD4G(B1, q1_, 4, w1t)                               \
    LD4G(B1, q2_, 8, w1t) LD4G(B1, q3_, 12, w1t)                              \
  }
#define CONSUME_C1(P)                                                         \
  {                                                                           \
    f32x2 c_ = {0.f, 0.f};                                                    \
    _Pragma("unroll") for (int s = 0; s < 16; ++s) c_ = pk_add(c_, B1[s]);    \
    c_ = pk_add(c_, bias1);                                                   \
    C1b[k & 1][(P)][lane] = c_;                                               \
  }
// C2: full LDS task (lgkm domain) — runs under C1's vm flight.
#define C2_TASK_LDS(P, C2Q)                                                   \
  {                                                                           \
    uint32_t ib_ = idx1b + (uint32_t)(((C2Q)&1) * (CH * 64)) + (uint32_t)((P)*64); \
    uint32_t rq_ = s1rb + (uint32_t)(((C2Q)&1) * (CH * 16)) + (uint32_t)((P)*16); \
    u32x4 q0_, q1_, q2_, q3_, qr_;                                            \
    DSR128(q0_, ib_, 0);                                                      \
    DSR128(q1_, ib_, 16);                                                     \
    DSR128(q2_, ib_, 32);                                                     \
    DSR128(q3_, ib_, 48);                                                     \
    DSR128(qr_, rq_, 0);                                                      \
    WAIT_LGKM(0);                                                             \
    LD4L(B2, q0_, 0) LD4L(B2, q1_, 4) LD4L(B2, q2_, 8) LD4L(B2, q3_, 12)      \
    u64 ta_ = (u64)qr_.x | ((u64)qr_.y << 32);                                \
    u64 tb_ = (u64)qr_.z | ((u64)qr_.w << 32);                                \
    WAIT_LGKM(0);                                                             \
    f32x2 c_ = {0.f, 0.f};                                                    \
    _Pragma("unroll") for (int s = 0; s < 16; ++s) c_ = pk_add(c_, B2[s]);    \
    while (ta_) { /* ranks >=16, exact ascending order */                     \
      uint32_t j_ = (uint32_t)__builtin_ctzll(ta_);                           \
      ta_ &= ta_ - 1;                                                         \
      f32x2 tw_;                                                              \
      DSR64(tw_, w2lb + (j_ << 9) + lane8, 0);                                \
      WAIT_LGKM(0);                                                           \
      c_ = pk_add(c_, tw_);                                                   \
    }                                                                         \
    while (tb_) {                                                             \
      uint32_t j_ = 64u + (uint32_t)__builtin_ctzll(tb_);                     \
      tb_ &= tb_ - 1;                                                         \
      f32x2 tw_;                                                              \
      DSR64(tw_, w2lb + (j_ << 9) + lane8, 0);                                \
      WAIT_LGKM(0);                                                           \
      c_ = pk_add(c_, tw_);                                                   \
    }                                                                         \
    c_ = pk_add(c_, bias2);                                                   \
    C2b[(C2Q)&1][(P)][lane] = c_;                                             \
  }
#define C3_TASK(T3)                                                           \
  {                                                                           \
    int c3_ = k - 4;                                                          \
    if (c3_ >= 0 && c3_ < NCH) {                                              \
      u64 a_ = rfl64(S2[c3_ & 1][(T3)][0]);                                   \
      u64 b_ = rfl64(S2[c3_ & 1][(T3)][1]);                                   \
      float v0 = (((a_ >> lane) & 1) ? w30a : 0.f) +                          \
                 (((b_ >> lane) & 1) ? w30b : 0.f);                           \
      float v1 = (((a_ >> lane) & 1) ? w31a : 0.f) +                          \
                 (((b_ >> lane) & 1) ? w31b : 0.f);                           \
      float r0 = wave_red_add63(v0);                                          \
      float r1 = wave_red_add63(v1);                                          \
      if (lane == 63) C3b[c3_ & 1][(T3)] = f32x2{r0 + b30, r1 + b31};         \
    }                                                                         \
  }

// ---- scan helpers: 16-wide issue groups, 2 groups per 32-step chunk ----
#define ISSUE16_512(ARR, A)                                                   \
  {                                                                           \
    DSR64(ARR[0], A, 0);     DSR64(ARR[1], A, 512);                           \
    DSR64(ARR[2], A, 1024);  DSR64(ARR[3], A, 1536);                          \
    DSR64(ARR[4], A, 2048);  DSR64(ARR[5], A, 2560);                          \
    DSR64(ARR[6], A, 3072);  DSR64(ARR[7], A, 3584);                          \
    DSR64(ARR[8], A, 4096);  DSR64(ARR[9], A, 4608);                          \
    DSR64(ARR[10], A, 5120); DSR64(ARR[11], A, 5632);                         \
    DSR64(ARR[12], A, 6144); DSR64(ARR[13], A, 6656);                         \
    DSR64(ARR[14], A, 7168); DSR64(ARR[15], A, 7680);                         \
  }
#define ISSUE16_8(ARR, A)                                                     \
  {                                                                           \
    DSR64(ARR[0], A, 0);   DSR64(ARR[1], A, 8);                               \
    DSR64(ARR[2], A, 16);  DSR64(ARR[3], A, 24);                              \
    DSR64(ARR[4], A, 32);  DSR64(ARR[5], A, 40);                              \
    DSR64(ARR[6], A, 48);  DSR64(ARR[7], A, 56);                              \
    DSR64(ARR[8], A, 64);  DSR64(ARR[9], A, 72);                              \
    DSR64(ARR[10], A, 80); DSR64(ARR[11], A, 88);                             \
    DSR64(ARR[12], A, 96); DSR64(ARR[13], A, 104);                            \
    DSR64(ARR[14], A, 112); DSR64(ARR[15], A, 120);                           \
  }
// scan1 group: 16 LIF1 steps + mbcnt scatter into 16-slot IDX1 + residuals.
#define SCAN1_G(P1, PR, TB)                                                   \
  _Pragma("unroll") for (int i = 0; i < 16; ++i) {                            \
    f32x2 cv_ = arr_[i];                                                      \
    float n0_ = __fadd_rn(__fmul_rn(0.9f, m1a), cv_.x);                       \
    float n1_ = __fadd_rn(__fmul_rn(0.9f, m1b), cv_.y);                       \
    m1a = (m1a > 1.f) ? (n0_ - 1.f) : n0_;                                    \
    m1b = (m1b > 1.f) ? (n1_ - 1.f) : n1_;                                    \
    u64 s0_ = __ballot(m1a > 1.f);                                            \
    u64 s1_ = __ballot(m1b > 1.f);                                            \
    uint32_t ib_ = (P1) + (uint32_t)(((TB) + i) * 64);                        \
    if (lane < 16) { DSW32(ib_ + (uint32_t)lane * 4u, 65536u); }              \
    uint32_t r0_ = mbcnt64(s0_);                                              \
    bool b0_ = ((s0_ >> lane) & 1) != 0;                                      \
    if (b0_ && r0_ < 16u) { DSW32(ib_ + r0_ * 4u, (uint32_t)lane << 9); }     \
    uint32_t c0_ = (uint32_t)__builtin_popcountll(s0_);                       \
    uint32_t r1_ = c0_ + mbcnt64(s1_);                                        \
    bool b1_ = ((s1_ >> lane) & 1) != 0;                                      \
    if (b1_ && r1_ < 16u) {                                                   \
      DSW32(ib_ + r1_ * 4u, (uint32_t)(64 + lane) << 9);                      \
    }                                                                         \
    u64 e0_ = __ballot(b0_ && r0_ >= 16u);                                    \
    u64 e1_ = __ballot(b1_ && r1_ >= 16u);                                    \
    if (lane == 0) {                                                          \
      DSW64((PR) + (uint32_t)(((TB) + i) * 16), e0_);                         \
      DSW64((PR) + (uint32_t)(((TB) + i) * 16 + 8), e1_);                     \
    }                                                                         \
  }
#define SCAN1(CHK)                                                            \
  {                                                                           \
    const int par_ = (CHK) & 1;                                               \
    const uint32_t rb_ = lds_addr32(&C1b[par_][0][0]) + lane8;                \
    const uint32_t p1_ = idx1b + (uint32_t)(par_ * (CH * 64));                \
    const uint32_t pr_ = s1rb + (uint32_t)(par_ * (CH * 16));                 \
    f32x2 arr_[16];                                                           \
    ISSUE16_512(arr_, rb_);                                                   \
    WAIT_LGKM(0);                                                             \
    SCAN1_G(p1_, pr_, 0)                                                      \
    ISSUE16_512(arr_, (rb_ + 8192u));                                         \
    WAIT_LGKM(0);                                                             \
    SCAN1_G(p1_, pr_, 16)                                                     \
    WAIT_LGKM(0);                                                             \
  }
#define SCAN2_G(SB, TB)                                                       \
  _Pragma("unroll") for (int i = 0; i < 16; ++i) {                            \
    f32x2 cv_ = arr_[i];                                                      \
    float n0_ = __fadd_rn(__fmul_rn(0.9f, m2a), cv_.x);                       \
    float n1_ = __fadd_rn(__fmul_rn(0.9f, m2b), cv_.y);                       \
    m2a = (m2a > 1.f) ? (n0_ - 1.f) : n0_;                                    \
    m2b = (m2b > 1.f) ? (n1_ - 1.f) : n1_;                                    \
    u64 s0_ = __ballot(m2a > 1.f);                                            \
    u64 s1_ = __ballot(m2b > 1.f);                                            \
    if (lane == 0)                                                            \
      ds_write_b128_at((SB) + (uint32_t)(((TB) + i) * 16),                    \
                       u32x4{(uint32_t)s0_, (uint32_t)(s0_ >> 32),            \
                             (uint32_t)s1_, (uint32_t)(s1_ >> 32)});          \
  }
#define SCAN2(CHK)                                                            \
  {                                                                           \
    const int par_ = (CHK) & 1;                                               \
    const uint32_t rb_ = lds_addr32(&C2b[par_][0][0]) + lane8;                \
    const uint32_t sb_ = lds_addr32(&S2[par_][0][0]);                         \
    f32x2 arr_[16];                                                           \
    ISSUE16_512(arr_, rb_);                                                   \
    WAIT_LGKM(0);                                                             \
    SCAN2_G(sb_, 0)                                                           \
    ISSUE16_512(arr_, (rb_ + 8192u));                                         \
    WAIT_LGKM(0);                                                             \
    SCAN2_G(sb_, 16)                                                          \
    WAIT_LGKM(0);                                                             \
  }
#define SCAN3_G(CHK, TB)                                                      \
  _Pragma("unroll") for (int i = 0; i < 16; ++i) {                            \
    f32x2 c3_ = arr_[i];                                                      \
    float e0_ = __fadd_rn(__fmul_rn(0.9f, m3x), c3_.x);                       \
    float e1_ = __fadd_rn(__fmul_rn(0.9f, m3y), c3_.y);                       \
    m3x = (m3x > 1.f) ? (e0_ - 1.f) : e0_;                                    \
    m3y = (m3y > 1.f) ? (e1_ - 1.f) : e1_;                                    \
    if (lane == 0)                                                            \
      outv[(size_t)((CHK)*CH + (TB) + i) * BB + b] = make_float2(m3x, m3y);   \
  }
#define SCAN3(CHK)                                                            \
  {                                                                           \
    const int par_ = (CHK) & 1;                                               \
    const uint32_t cb_ = lds_addr32(&C3b[par_][0]);                           \
    f32x2 arr_[16];                                                           \
    ISSUE16_8(arr_, cb_);                                                     \
    WAIT_LGKM(0);                                                             \
    SCAN3_G(CHK, 0)                                                           \
    ISSUE16_8(arr_, (cb_ + 128u));                                            \
    WAIT_LGKM(0);                                                             \
    SCAN3_G(CHK, 16)                                                          \
  }

  // ================= chunk-synchronous main pipeline =================
  for (int k = 0; k < NCH + 5; ++k) {
    __syncthreads();
    if (wv < NPROD) {
      const bool doC1 = (k < NCH);
      const int c2q = k - 2;
      const bool doC2 = (c2q >= 0) && (c2q < NCH);
      f32x2 B1[16], B2[16];
      if (doC1 && doC2) {
        // pipe-split steady state: C1 (vm) in flight under the C2 LDS task.
        for (int p = wv; p < CH; p += NPROD) {
          ISSUE_C1(p);          // 16 global loads outstanding (vm)
          C2_TASK_LDS(p, c2q);  // entire C2 task on lgkm pipe
          WAIT_VM(0);           // C1 landed (hidden under C2 work)
          CONSUME_C1(p);
        }
      } else if (doC1) {
        for (int p = wv; p < CH; p += NPROD) {
          ISSUE_C1(p);
          WAIT_VM(0);
          CONSUME_C1(p);
        }
      } else if (doC2) {
        for (int p = wv; p < CH; p += NPROD) {
          C2_TASK_LDS(p, c2q);
        }
      }
      for (int t3 = wv; t3 < CH; t3 += NPROD) {
        C3_TASK(t3);
      }
    } else if (wv == 13) {
      if (k >= 1 && k - 1 < NCH) SCAN1(k - 1);
    } else if (wv == 14) {
      if (k >= 3 && k - 3 < NCH) SCAN2(k - 3);
      if (k >= 5 && k - 5 < NCH) SCAN3(k - 5);
    } else {
      IDX0_BUILD(k + 1);
    }
  }
#undef SCAN3
#undef SCAN3_G
#undef SCAN2
#undef SCAN2_G
#undef SCAN1
#undef SCAN1_G
#undef ISSUE16_8
#undef ISSUE16_512
#undef C3_TASK
#undef C2_TASK_LDS
#undef CONSUME_C1
#undef ISSUE_C1
#undef LD4L
#undef LD4G
#undef IDX0_BUILD
}

extern "C" void kernel_launch(void* const* d_in, const int* in_sizes, int n_in,
                              void* d_out, int out_size, void* d_ws,
                              size_t ws_size, hipStream_t stream) {
  const float* x = (const float*)d_in[0];
  const float* W1 = (const float*)d_in[1];
  const float* b1 = (const float*)d_in[2];
  const float* W2 = (const float*)d_in[3];
  const float* b2 = (const float*)d_in[4];
  const float* W3 = (const float*)d_in[5];
  const float* b3 = (const float*)d_in[6];
  float* out = (float*)d_out;

  uint32_t* masks = (uint32_t*)d_ws;                         // 4 MiB
  char* wbase = (char*)d_ws + (size_t)BB * TT * 4;
  f32x2* w1t = (f32x2*)wbase;                                // 32768 B
  f32x2* w2t = (f32x2*)(wbase + 32768);                      // 66048 B

  snn_prep<<<1, 64, 0, stream>>>(W1, W2, w1t, w2t);
  snn_encode<<<BB / 4, 64, 0, stream>>>(x, masks);
  snn_core17<<<BB, NTHR, 0, stream>>>(masks, w1t, w2t, b1, b2, W3, b3, out);
}